// Round 1
// baseline (6647.791 us; speedup 1.0000x reference)
//
#include <hip/hip_runtime.h>

#define N_ATOM 100000
#define M_NBR  12
#define NF     41
#define AF     64
#define NC     3
#define N0C    100
#define APC    1000
#define HF     128
#define HID    64
#define EPS    1e-5f

typedef unsigned short u16;

__device__ __forceinline__ float b2f(u16 u) {
    return __uint_as_float(((unsigned int)u) << 16);
}
__device__ __forceinline__ u16 f2b(float f) {
    unsigned int x = __float_as_uint(f);
    unsigned int r = x + 0x7fffu + ((x >> 16) & 1u);
    return (u16)(r >> 16);
}
// dtype-flexible load: f==1 -> buffer is float32, else bf16
__device__ __forceinline__ float ldf(const void* p, long i, int f) {
    if (f) return ((const float*)p)[i];
    return b2f(((const u16*)p)[i]);
}
__device__ __forceinline__ float spf(float x) {           // softplus, stable
    return fmaxf(x, 0.0f) + log1pf(expf(-fabsf(x)));
}
__device__ __forceinline__ float sigf(float x) {
    return 1.0f / (1.0f + expf(-x));
}

// ---- dtype probe: decode first 8192 u16 of nbr_fea as bf16; count implausible ----
__global__ void k_probe(const u16* __restrict__ nf, int* __restrict__ flag) {
    int t = threadIdx.x;  // 256
    int bad = 0;
    for (int i = t; i < 8192; i += 256) {
        u16 u = nf[i];
        float v = b2f(u);
        float a = fabsf(v);
        if (!(a <= 1024.0f) || (((u & 0x7fffu) != 0) && a < 1e-10f)) bad++;
    }
    __shared__ int cnt;
    if (t == 0) cnt = 0;
    __syncthreads();
    atomicAdd(&cnt, bad);
    __syncthreads();
    if (t == 0) flag[0] = (cnt > 800) ? 1 : 0;
}

// ---- stage layer params into fp32 ws buffers (dtype-agnostic downstream) ----
__global__ void k_stage(const void* __restrict__ W, long Woff,
                        const void* __restrict__ b, long boff,
                        const void* __restrict__ g1, const void* __restrict__ b1,
                        const void* __restrict__ g2, const void* __restrict__ b2, long L,
                        float* __restrict__ Wst, float* __restrict__ bst,
                        float* __restrict__ bn1s, float* __restrict__ bn2s,
                        const int* __restrict__ flag) {
    int f = flag[0];
    long i = (long)blockIdx.x * 256 + threadIdx.x;
    const long NW_ = (long)(2 * AF + NF) * 128;  // 21632
    if (i < NW_) {
        Wst[i] = ldf(W, Woff + i, f);
    } else if (i < NW_ + 128) {
        long c = i - NW_;
        bst[c] = ldf(b, boff + c, f);
        bn1s[c] = ldf(g1, L * 128 + c, f);
        bn1s[128 + c] = ldf(b1, L * 128 + c, f);
        if (c < 64) {
            bn2s[c] = ldf(g2, L * 64 + c, f);
            bn2s[64 + c] = ldf(b2, L * 64 + c, f);
        }
    }
}

// ---- atom_fea = embedding[atom_num], stored bf16 in ws ----
__global__ void k_embed(const int* __restrict__ atom_num, const void* __restrict__ emb,
                        u16* __restrict__ af, const int* __restrict__ flag) {
    int f = flag[0];
    int i = blockIdx.x * 256 + threadIdx.x;
    if (i < N_ATOM * AF) {
        int n = i >> 6, c = i & 63;
        af[i] = f2b(ldf(emb, (long)atom_num[n] * AF + c, f));
    }
}

// ---- An = af @ W[64:128] (fp32 staged W), stored bf16. one wave/atom, 2 ch/lane.
// af row is wave-uniform -> scalar (SGPR) loads, no shuffles.
__global__ __launch_bounds__(256) void k_an(const u16* __restrict__ af,
                       const float* __restrict__ Wst, u16* __restrict__ An) {
    int lane = threadIdx.x & 63;
    int n = __builtin_amdgcn_readfirstlane(blockIdx.x * 4 + (threadIdx.x >> 6));
    const unsigned int* ap = (const unsigned int*)af + ((long)n << 5);  // 32 dwords = 64 bf16
    float a0 = 0.f, a1 = 0.f;
    #pragma unroll
    for (int kk = 0; kk < 32; ++kk) {
        unsigned int w = ap[kk];
        float alo = b2f((u16)(w & 0xffffu));
        float ahi = b2f((u16)(w >> 16));
        const float* wr = Wst + (AF + (kk << 1)) * 128 + lane;
        a0 = fmaf(alo, wr[0], a0);
        a1 = fmaf(alo, wr[64], a1);
        a0 = fmaf(ahi, wr[128], a0);
        a1 = fmaf(ahi, wr[192], a1);
    }
    An[(long)n * 128 + lane] = f2b(a0);
    An[(long)n * 128 + 64 + lane] = f2b(a1);
}

// ---- conv sweep. As recomputed per atom from staged fp32 W.
// APPLY=false -> bn1 stats; true -> apply bn1 + gate + summed + bn2 stats.
// RECOMP_AN: low-ws path recomputes An[j] per edge instead of reading it.
// All per-edge broadcast values (nbr_fea row, af rows) are wave-uniform:
// readfirstlane forces uniform addresses/control-flow -> scalar loads,
// removing the serialized ds_bpermute->fma latency chains.
template<bool APPLY, bool RECOMP_AN>
__global__ __launch_bounds__(256) void k_conv(const void* __restrict__ nbr_fea,
                       const int* __restrict__ nbr_idx,
                       const u16* __restrict__ af, const u16* __restrict__ An,
                       const float* __restrict__ Wst, const float* __restrict__ bst,
                       const float* __restrict__ st1,   // [0:128]=scale [128:256]=shift
                       u16* __restrict__ summed,
                       float* __restrict__ statsOut,
                       const int* __restrict__ flag) {
    int f = flag[0];
    int lane = threadIdx.x & 63;
    int gw = __builtin_amdgcn_readfirstlane(blockIdx.x * 4 + (threadIdx.x >> 6));
    int NW = gridDim.x * 4;
    // register-resident W_edge columns {lane, lane+64}; rows 128..168
    float w0[NF], w1[NF];
    #pragma unroll
    for (int k = 0; k < NF; ++k) {
        w0[k] = Wst[(128 + k) * 128 + lane];
        w1[k] = Wst[(128 + k) * 128 + 64 + lane];
    }
    float b0 = bst[lane];
    float b1 = bst[64 + lane];
    float s0 = 0.f, t0 = 0.f, s1 = 0.f, t1 = 0.f;
    if (APPLY) {
        s0 = st1[lane];        s1 = st1[lane + 64];
        t0 = st1[128 + lane];  t1 = st1[192 + lane];
    }
    float sum0 = 0.f, ssq0 = 0.f, sum1 = 0.f, ssq1 = 0.f;
    for (int n = gw; n < N_ATOM; n += NW) {
        // As = af[n] @ W[0:64] + b  -- af row uniform -> scalar loads
        const unsigned int* ap = (const unsigned int*)af + ((long)n << 5);
        float as0 = b0, as1 = b1;
        #pragma unroll
        for (int kk = 0; kk < 32; ++kk) {
            unsigned int w = ap[kk];
            float alo = b2f((u16)(w & 0xffffu));
            float ahi = b2f((u16)(w >> 16));
            const float* wr = Wst + (kk << 1) * 128 + lane;
            as0 = fmaf(alo, wr[0], as0);
            as1 = fmaf(alo, wr[64], as1);
            as0 = fmaf(ahi, wr[128], as0);
            as1 = fmaf(ahi, wr[192], as1);
        }
        float asum = 0.f;
        for (int m = 0; m < M_NBR; ++m) {
            long r = (long)n * M_NBR + m;
            int j = nbr_idx[r];
            float e0 = as0, e1 = as1;
            if (f) {
                // fp32 nbr row, wave-uniform -> scalar loads + SGPR-operand fma
                const float* np = (const float*)nbr_fea + r * NF;
                #pragma unroll
                for (int k = 0; k < NF; ++k) {
                    float v = np[k];
                    e0 = fmaf(v, w0[k], e0);
                    e1 = fmaf(v, w1[k], e1);
                }
            } else {
                // legacy bf16 path (unaligned for scalar dword loads): shuffle broadcast
                float nv = (lane < NF) ? b2f(((const u16*)nbr_fea)[r * NF + lane]) : 0.f;
                #pragma unroll
                for (int k = 0; k < NF; ++k) {
                    float v = __shfl(nv, k, 64);
                    e0 = fmaf(v, w0[k], e0);
                    e1 = fmaf(v, w1[k], e1);
                }
            }
            float g0, g1;
            if (RECOMP_AN) {
                int ju = __builtin_amdgcn_readfirstlane(j);
                const unsigned int* ajp = (const unsigned int*)af + ((long)ju << 5);
                float an0 = 0.f, an1 = 0.f;
                #pragma unroll
                for (int kk = 0; kk < 32; ++kk) {
                    unsigned int w = ajp[kk];
                    float alo = b2f((u16)(w & 0xffffu));
                    float ahi = b2f((u16)(w >> 16));
                    const float* wr = Wst + (AF + (kk << 1)) * 128 + lane;
                    an0 = fmaf(alo, wr[0], an0);
                    an1 = fmaf(alo, wr[64], an1);
                    an0 = fmaf(ahi, wr[128], an0);
                    an1 = fmaf(ahi, wr[192], an1);
                }
                g0 = e0 + an0; g1 = e1 + an1;
            } else {
                g0 = e0 + b2f(An[(long)j * 128 + lane]);
                g1 = e1 + b2f(An[(long)j * 128 + 64 + lane]);
            }
            if (APPLY) {
                float ft = sigf(fmaf(g0, s0, t0));
                float cc = spf(fmaf(g1, s1, t1));
                asum += ft * cc;
            } else {
                sum0 += g0; ssq0 += g0 * g0;
                sum1 += g1; ssq1 += g1 * g1;
            }
        }
        if (APPLY) {
            summed[(long)n * 64 + lane] = f2b(asum);
            sum0 += asum; ssq0 += asum * asum;
        }
    }
    __shared__ float red[256];
    if (APPLY) {
        if (threadIdx.x < 128) red[threadIdx.x] = 0.f;
        __syncthreads();
        atomicAdd(&red[lane], sum0);
        atomicAdd(&red[64 + lane], ssq0);
        __syncthreads();
        if (threadIdx.x < 128) atomicAdd(&statsOut[threadIdx.x], red[threadIdx.x]);
    } else {
        red[threadIdx.x] = 0.f;
        __syncthreads();
        atomicAdd(&red[lane], sum0);
        atomicAdd(&red[64 + lane], sum1);
        atomicAdd(&red[128 + lane], ssq0);
        atomicAdd(&red[192 + lane], ssq1);
        __syncthreads();
        atomicAdd(&statsOut[threadIdx.x], red[threadIdx.x]);
    }
}

__global__ void k_bn1(const float* __restrict__ stats, const float* __restrict__ bn1s,
                      float* __restrict__ st) {
    int c = threadIdx.x;  // 128
    float cnt = (float)N_ATOM * (float)M_NBR;
    float mu = stats[c] / cnt;
    float var = fmaxf(stats[128 + c] / cnt - mu * mu, 0.0f);
    float s = bn1s[c] * rsqrtf(var + EPS);
    st[c] = s;
    st[128 + c] = bn1s[128 + c] - mu * s;
}

__global__ void k_bn2(const float* __restrict__ stats, const float* __restrict__ bn2s,
                      float* __restrict__ st) {
    int c = threadIdx.x;  // 64
    float cnt = (float)N_ATOM;
    float mu = stats[c] / cnt;
    float var = fmaxf(stats[64 + c] / cnt - mu * mu, 0.0f);
    float s = bn2s[c] * rsqrtf(var + EPS);
    st[c] = s;
    st[64 + c] = bn2s[64 + c] - mu * s;
}

__global__ void k_update(u16* __restrict__ af, const u16* __restrict__ summed,
                         const float* __restrict__ st2) {
    int i = blockIdx.x * 256 + threadIdx.x;
    if (i < N_ATOM * 64) {
        int c = i & 63;
        float v = fmaf(b2f(summed[i]), st2[c], st2[64 + c]);
        af[i] = f2b(spf(b2f(af[i]) + v));
    }
}

__global__ void k_pool(const u16* __restrict__ af, const int* __restrict__ cidx,
                       float* __restrict__ crysp) {
    int b = blockIdx.x;
    int ch = threadIdx.x & 63;
    int part = threadIdx.x >> 6;
    float acc = 0.f;
    for (int k = part; k < APC; k += 4) {
        int a = cidx[b * APC + k];
        acc += b2f(af[(long)a * 64 + ch]);
    }
    __shared__ float red[256];
    red[threadIdx.x] = acc;
    __syncthreads();
    if (part == 0) {
        float s = red[ch] + red[64 + ch] + red[128 + ch] + red[192 + ch];
        crysp[b * 64 + ch] = spf(s * (1.0f / APC));
    }
}

__global__ void k_head(const float* __restrict__ crysp, const void* __restrict__ Wfc,
                       const void* __restrict__ bfc, const void* __restrict__ Wout,
                       const void* __restrict__ bout, void* __restrict__ outv,
                       const int* __restrict__ flag) {
    int f = flag[0];
    int b = blockIdx.x;
    int t = threadIdx.x;  // 128
    __shared__ float cr[64];
    __shared__ float h[HF];
    if (t < 64) cr[t] = crysp[b * 64 + t];
    __syncthreads();
    float acc = ldf(bfc, t, f);
    for (int k = 0; k < 64; ++k) acc = fmaf(cr[k], ldf(Wfc, (long)k * HF + t, f), acc);
    h[t] = spf(acc);
    __syncthreads();
    if (t < HID) {
        float o = ldf(bout, t, f);
        for (int k = 0; k < HF; ++k) o = fmaf(h[k], ldf(Wout, (long)k * HID + t, f), o);
        if (f) ((float*)outv)[b * HID + t] = o;
        else   ((u16*)outv)[b * HID + t] = f2b(o);
    }
}

extern "C" void kernel_launch(void* const* d_in, const int* in_sizes, int n_in,
                              void* d_out, int out_size, void* d_ws, size_t ws_size,
                              hipStream_t stream) {
    const int* atom_num = (const int*)d_in[0];
    const void* nbr_fea = d_in[1];
    const int* nbr_idx  = (const int*)d_in[2];
    const int* cidx     = (const int*)d_in[3];
    const void* emb     = d_in[4];
    const void* W_full  = d_in[5];
    const void* b_full  = d_in[6];
    const void* bn1_g   = d_in[7];
    const void* bn1_b   = d_in[8];
    const void* bn2_g   = d_in[9];
    const void* bn2_b   = d_in[10];
    const void* W_fc    = d_in[11];
    const void* b_fc    = d_in[12];
    const void* W_out   = d_in[13];
    const void* b_out   = d_in[14];

    // ---- ws layout: control + staging first, big arrays after ----
    char* wsb = (char*)d_ws;
    int*   flag   = (int*)wsb;                          // 16 B
    float* stats1 = (float*)(wsb + 16);                 // 256
    float* st1    = stats1 + 256;                       // 256
    float* stats2 = st1 + 256;                          // 128
    float* st2    = stats2 + 128;                       // 128
    float* crysp  = st2 + 128;                          // 6400
    float* Wst    = crysp + 6400;                       // 21632
    float* bst    = Wst + 21632;                        // 128
    float* bn1s   = bst + 128;                          // 256
    float* bn2s   = bn1s + 256;                         // 128
    u16*   af     = (u16*)(bn2s + 128);                 // N*64 bf16 = 12.8 MB
    u16*   summed = af + (long)N_ATOM * 64;             // N*64 bf16 = 12.8 MB
    u16*   An     = summed + (long)N_ATOM * 64;         // N*128 bf16 = 25.6 MB (fast path)
    size_t need_fast = (size_t)((char*)(An + (long)N_ATOM * 128) - wsb);
    bool fast = ws_size >= need_fast;

    k_probe<<<1, 256, 0, stream>>>((const u16*)nbr_fea, flag);
    k_embed<<<(N_ATOM * 64 + 255) / 256, 256, 0, stream>>>(atom_num, emb, af, flag);

    const long WROWS = (long)(2 * AF + NF) * 128;  // 21632
    for (int L = 0; L < NC; ++L) {
        hipMemsetAsync(stats1, 0, 768 * sizeof(float), stream);
        k_stage<<<(int)((WROWS + 128 + 255) / 256), 256, 0, stream>>>(
            W_full, (long)L * WROWS, b_full, (long)L * 128,
            bn1_g, bn1_b, bn2_g, bn2_b, (long)L,
            Wst, bst, bn1s, bn2s, flag);
        if (fast) {
            k_an<<<N_ATOM / 4, 256, 0, stream>>>(af, Wst, An);
            k_conv<false, false><<<2500, 256, 0, stream>>>(nbr_fea, nbr_idx, af, An,
                                                           Wst, bst, nullptr, nullptr, stats1, flag);
        } else {
            k_conv<false, true><<<2500, 256, 0, stream>>>(nbr_fea, nbr_idx, af, nullptr,
                                                          Wst, bst, nullptr, nullptr, stats1, flag);
        }
        k_bn1<<<1, 128, 0, stream>>>(stats1, bn1s, st1);
        if (fast) {
            k_conv<true, false><<<2500, 256, 0, stream>>>(nbr_fea, nbr_idx, af, An,
                                                          Wst, bst, st1, summed, stats2, flag);
        } else {
            k_conv<true, true><<<2500, 256, 0, stream>>>(nbr_fea, nbr_idx, af, nullptr,
                                                         Wst, bst, st1, summed, stats2, flag);
        }
        k_bn2<<<1, 64, 0, stream>>>(stats2, bn2s, st2);
        k_update<<<(N_ATOM * 64 + 255) / 256, 256, 0, stream>>>(af, summed, st2);
    }
    k_pool<<<N0C, 256, 0, stream>>>(af, cidx, crysp);
    k_head<<<N0C, HF, 0, stream>>>(crysp, W_fc, b_fc, W_out, b_out, d_out, flag);
}

// Round 2
// 3991.477 us; speedup vs baseline: 1.6655x; 1.6655x over previous
//
#include <hip/hip_runtime.h>

#define N_ATOM 100000
#define M_NBR  12
#define NF     41
#define AF     64
#define NC     3
#define N0C    100
#define APC    1000
#define HF     128
#define HID    64
#define EPS    1e-5f

typedef unsigned short u16;
typedef unsigned int   u32;

__device__ __forceinline__ float b2f(u16 u) {
    return __uint_as_float(((u32)u) << 16);
}
__device__ __forceinline__ u16 f2b(float f) {
    u32 x = __float_as_uint(f);
    u32 r = x + 0x7fffu + ((x >> 16) & 1u);
    return (u16)(r >> 16);
}
// dtype-flexible load: f==1 -> buffer is float32, else bf16
__device__ __forceinline__ float ldf(const void* p, long i, int f) {
    if (f) return ((const float*)p)[i];
    return b2f(((const u16*)p)[i]);
}
__device__ __forceinline__ float spf(float x) {           // softplus, stable
    return fmaxf(x, 0.0f) + log1pf(expf(-fabsf(x)));
}
__device__ __forceinline__ float sigf(float x) {
    return 1.0f / (1.0f + expf(-x));
}
// guaranteed v_readlane broadcast (compile-time lane, SGPR result, no ds_bpermute)
__device__ __forceinline__ float rdl(float v, int l) {
    return __uint_as_float((u32)__builtin_amdgcn_readlane(__float_as_uint(v), l));
}

// ---- dtype probe: decode first 8192 u16 of nbr_fea as bf16; count implausible ----
__global__ void k_probe(const u16* __restrict__ nf, int* __restrict__ flag) {
    int t = threadIdx.x;  // 256
    int bad = 0;
    for (int i = t; i < 8192; i += 256) {
        u16 u = nf[i];
        float v = b2f(u);
        float a = fabsf(v);
        if (!(a <= 1024.0f) || (((u & 0x7fffu) != 0) && a < 1e-10f)) bad++;
    }
    __shared__ int cnt;
    if (t == 0) cnt = 0;
    __syncthreads();
    atomicAdd(&cnt, bad);
    __syncthreads();
    if (t == 0) flag[0] = (cnt > 800) ? 1 : 0;
}

// ---- stage layer params into fp32 ws buffers (dtype-agnostic downstream) ----
__global__ void k_stage(const void* __restrict__ W, long Woff,
                        const void* __restrict__ b, long boff,
                        const void* __restrict__ g1, const void* __restrict__ b1,
                        const void* __restrict__ g2, const void* __restrict__ b2, long L,
                        float* __restrict__ Wst, float* __restrict__ bst,
                        float* __restrict__ bn1s, float* __restrict__ bn2s,
                        const int* __restrict__ flag) {
    int f = flag[0];
    long i = (long)blockIdx.x * 256 + threadIdx.x;
    const long NW_ = (long)(2 * AF + NF) * 128;  // 21632
    if (i < NW_) {
        Wst[i] = ldf(W, Woff + i, f);
    } else if (i < NW_ + 128) {
        long c = i - NW_;
        bst[c] = ldf(b, boff + c, f);
        bn1s[c] = ldf(g1, L * 128 + c, f);
        bn1s[128 + c] = ldf(b1, L * 128 + c, f);
        if (c < 64) {
            bn2s[c] = ldf(g2, L * 64 + c, f);
            bn2s[64 + c] = ldf(b2, L * 64 + c, f);
        }
    }
}

// ---- atom_fea = embedding[atom_num], stored bf16 in ws ----
__global__ void k_embed(const int* __restrict__ atom_num, const void* __restrict__ emb,
                        u16* __restrict__ af, const int* __restrict__ flag) {
    int f = flag[0];
    int i = blockIdx.x * 256 + threadIdx.x;
    if (i < N_ATOM * AF) {
        int n = i >> 6, c = i & 63;
        af[i] = f2b(ldf(emb, (long)atom_num[n] * AF + c, f));
    }
}

// ---- round-0 k_an (MODE=1 fallback): An = af @ W[64:128], unpacked layout ----
__global__ __launch_bounds__(256) void k_an(const u16* __restrict__ af,
                       const float* __restrict__ Wst, u16* __restrict__ An) {
    int wv = threadIdx.x >> 6;
    int lane = threadIdx.x & 63;
    int n = blockIdx.x * 4 + wv;
    float afv = b2f(af[n * AF + lane]);
    float a0 = 0.f, a1 = 0.f;
    for (int k = 0; k < AF; ++k) {
        float a = __shfl(afv, k, 64);
        a0 = fmaf(a, Wst[(AF + k) * 128 + lane], a0);
        a1 = fmaf(a, Wst[(AF + k) * 128 + 64 + lane], a1);
    }
    An[(long)n * 128 + lane] = f2b(a0);
    An[(long)n * 128 + 64 + lane] = f2b(a1);
}

// ---- MODE=0 precompute: R = af@W[0:64]+b (fp32 or bf16), An2 = af@W[64:128] (packed bf16) ----
// Accumulation order matches the round-0 in-kernel As exactly (bitwise identical when rf=1).
__global__ __launch_bounds__(256) void k_asn(const u16* __restrict__ af,
                       const float* __restrict__ Wst, const float* __restrict__ bst,
                       float* __restrict__ Rf, u16* __restrict__ Rh,
                       u16* __restrict__ An2, int rf) {
    int lane = threadIdx.x & 63;
    int n = blockIdx.x * 4 + (threadIdx.x >> 6);
    float afv = b2f(af[n * AF + lane]);
    float r0 = bst[lane], r1 = bst[64 + lane];
    float q0 = 0.f, q1 = 0.f;
    for (int k = 0; k < AF; ++k) {
        float a = __shfl(afv, k, 64);
        r0 = fmaf(a, Wst[k * 128 + lane], r0);
        r1 = fmaf(a, Wst[k * 128 + 64 + lane], r1);
        q0 = fmaf(a, Wst[(AF + k) * 128 + lane], q0);
        q1 = fmaf(a, Wst[(AF + k) * 128 + 64 + lane], q1);
    }
    long p = (long)n * 64 + lane;
    if (rf) {
        *(float2*)(Rf + p * 2) = make_float2(r0, r1);
    } else {
        ((u32*)Rh)[p] = (u32)f2b(r0) | ((u32)f2b(r1) << 16);
    }
    ((u32*)An2)[p] = (u32)f2b(q0) | ((u32)f2b(q1) << 16);
}

// ---- conv sweep.
// MODE 0: R & An precomputed (packed); 2-edge unroll, readlane broadcast.
// MODE 1: round-0 fast (As in-kernel, An read, unpacked layout).
// MODE 2: round-0 slow (As + An in-kernel).
// APPLY=false -> bn1 stats; true -> apply bn1 + gate + summed + bn2 stats.
template<bool APPLY, int MODE>
__global__ __launch_bounds__(256, 4) void k_conv(const void* __restrict__ nbr_fea,
                       const int* __restrict__ nbr_idx,
                       const u16* __restrict__ af, const u16* __restrict__ An,
                       const float* __restrict__ Wst, const float* __restrict__ bst,
                       const float* __restrict__ st1,   // [0:128]=scale [128:256]=shift
                       u16* __restrict__ summed,
                       float* __restrict__ statsOut,
                       const int* __restrict__ flag,
                       const float* __restrict__ Rf, const u16* __restrict__ Rh, int rf) {
    int f = flag[0];
    int lane = threadIdx.x & 63;
    int wv = threadIdx.x >> 6;
    int gwave = blockIdx.x * 4 + wv;
    int NW = gridDim.x * 4;
    // register-resident W_edge columns {lane, lane+64}; rows 128..168
    float w0[NF], w1[NF];
    #pragma unroll
    for (int k = 0; k < NF; ++k) {
        w0[k] = Wst[(128 + k) * 128 + lane];
        w1[k] = Wst[(128 + k) * 128 + 64 + lane];
    }
    float s0 = 0.f, t0 = 0.f, s1 = 0.f, t1 = 0.f;
    if (APPLY) {
        s0 = st1[lane];        s1 = st1[lane + 64];
        t0 = st1[128 + lane];  t1 = st1[192 + lane];
    }
    float sum0 = 0.f, ssq0 = 0.f, sum1 = 0.f, ssq1 = 0.f;

    if (MODE == 0) {
        for (int n = gwave; n < N_ATOM; n += NW) {
            long p = (long)n * 64 + lane;
            float r0, r1;
            if (rf) {
                float2 rr = *(const float2*)(Rf + p * 2);
                r0 = rr.x; r1 = rr.y;
            } else {
                u32 rr = ((const u32*)Rh)[p];
                r0 = b2f((u16)(rr & 0xffffu)); r1 = b2f((u16)(rr >> 16));
            }
            float asum = 0.f;
            for (int m = 0; m < M_NBR; m += 2) {
                long ra = (long)n * M_NBR + m;
                int2 jj = *(const int2*)(nbr_idx + ra);
                float nv0, nv1;
                if (f) {
                    const float* np = (const float*)nbr_fea + ra * NF;
                    nv0 = (lane < NF) ? np[lane] : 0.f;
                    nv1 = (lane < NF) ? np[NF + lane] : 0.f;
                } else {
                    const u16* np = (const u16*)nbr_fea + ra * NF;
                    nv0 = (lane < NF) ? b2f(np[lane]) : 0.f;
                    nv1 = (lane < NF) ? b2f(np[NF + lane]) : 0.f;
                }
                u32 qa = ((const u32*)An)[(long)jj.x * 64 + lane];
                u32 qb = ((const u32*)An)[(long)jj.y * 64 + lane];
                float ea0 = r0, ea1 = r1, eb0 = r0, eb1 = r1;
                #pragma unroll
                for (int k = 0; k < NF; ++k) {
                    float va = rdl(nv0, k);
                    float vb = rdl(nv1, k);
                    ea0 = fmaf(va, w0[k], ea0);
                    ea1 = fmaf(va, w1[k], ea1);
                    eb0 = fmaf(vb, w0[k], eb0);
                    eb1 = fmaf(vb, w1[k], eb1);
                }
                float ga0 = ea0 + b2f((u16)(qa & 0xffffu));
                float ga1 = ea1 + b2f((u16)(qa >> 16));
                float gb0 = eb0 + b2f((u16)(qb & 0xffffu));
                float gb1 = eb1 + b2f((u16)(qb >> 16));
                if (APPLY) {
                    asum += sigf(fmaf(ga0, s0, t0)) * spf(fmaf(ga1, s1, t1));
                    asum += sigf(fmaf(gb0, s0, t0)) * spf(fmaf(gb1, s1, t1));
                } else {
                    sum0 += ga0 + gb0; ssq0 += ga0 * ga0 + gb0 * gb0;
                    sum1 += ga1 + gb1; ssq1 += ga1 * ga1 + gb1 * gb1;
                }
            }
            if (APPLY) {
                summed[p] = f2b(asum);
                sum0 += asum; ssq0 += asum * asum;
            }
        }
    } else {
        float b0 = bst[lane];
        float b1 = bst[64 + lane];
        for (int n = gwave; n < N_ATOM; n += NW) {
            // As = af[n] @ W[0:64] + b
            float afv = b2f(af[n * AF + lane]);
            float as0 = b0, as1 = b1;
            for (int k = 0; k < AF; ++k) {
                float a = __shfl(afv, k, 64);
                as0 = fmaf(a, Wst[k * 128 + lane], as0);
                as1 = fmaf(a, Wst[k * 128 + 64 + lane], as1);
            }
            float asum = 0.f;
            for (int m = 0; m < M_NBR; ++m) {
                long r = (long)n * M_NBR + m;
                int j = nbr_idx[r];
                float nv = (lane < NF) ? ldf(nbr_fea, r * NF + lane, f) : 0.f;
                float e0 = as0, e1 = as1;
                #pragma unroll
                for (int k = 0; k < NF; ++k) {
                    float v = __shfl(nv, k, 64);
                    e0 = fmaf(v, w0[k], e0);
                    e1 = fmaf(v, w1[k], e1);
                }
                float g0, g1;
                if (MODE == 2) {
                    float aj = b2f(af[(long)j * AF + lane]);
                    float an0 = 0.f, an1 = 0.f;
                    for (int k = 0; k < AF; ++k) {
                        float a = __shfl(aj, k, 64);
                        an0 = fmaf(a, Wst[(AF + k) * 128 + lane], an0);
                        an1 = fmaf(a, Wst[(AF + k) * 128 + 64 + lane], an1);
                    }
                    g0 = e0 + an0; g1 = e1 + an1;
                } else {
                    g0 = e0 + b2f(An[(long)j * 128 + lane]);
                    g1 = e1 + b2f(An[(long)j * 128 + 64 + lane]);
                }
                if (APPLY) {
                    float ft = sigf(fmaf(g0, s0, t0));
                    float cc = spf(fmaf(g1, s1, t1));
                    asum += ft * cc;
                } else {
                    sum0 += g0; ssq0 += g0 * g0;
                    sum1 += g1; ssq1 += g1 * g1;
                }
            }
            if (APPLY) {
                summed[(long)n * 64 + lane] = f2b(asum);
                sum0 += asum; ssq0 += asum * asum;
            }
        }
    }

    __shared__ float red[256];
    if (APPLY) {
        if (threadIdx.x < 128) red[threadIdx.x] = 0.f;
        __syncthreads();
        atomicAdd(&red[lane], sum0);
        atomicAdd(&red[64 + lane], ssq0);
        __syncthreads();
        if (threadIdx.x < 128) atomicAdd(&statsOut[threadIdx.x], red[threadIdx.x]);
    } else {
        red[threadIdx.x] = 0.f;
        __syncthreads();
        atomicAdd(&red[lane], sum0);
        atomicAdd(&red[64 + lane], sum1);
        atomicAdd(&red[128 + lane], ssq0);
        atomicAdd(&red[192 + lane], ssq1);
        __syncthreads();
        atomicAdd(&statsOut[threadIdx.x], red[threadIdx.x]);
    }
}

__global__ void k_bn1(const float* __restrict__ stats, const float* __restrict__ bn1s,
                      float* __restrict__ st) {
    int c = threadIdx.x;  // 128
    float cnt = (float)N_ATOM * (float)M_NBR;
    float mu = stats[c] / cnt;
    float var = fmaxf(stats[128 + c] / cnt - mu * mu, 0.0f);
    float s = bn1s[c] * rsqrtf(var + EPS);
    st[c] = s;
    st[128 + c] = bn1s[128 + c] - mu * s;
}

__global__ void k_bn2(const float* __restrict__ stats, const float* __restrict__ bn2s,
                      float* __restrict__ st) {
    int c = threadIdx.x;  // 64
    float cnt = (float)N_ATOM;
    float mu = stats[c] / cnt;
    float var = fmaxf(stats[64 + c] / cnt - mu * mu, 0.0f);
    float s = bn2s[c] * rsqrtf(var + EPS);
    st[c] = s;
    st[64 + c] = bn2s[64 + c] - mu * s;
}

__global__ void k_update(u16* __restrict__ af, const u16* __restrict__ summed,
                         const float* __restrict__ st2) {
    int i = blockIdx.x * 256 + threadIdx.x;
    if (i < N_ATOM * 64) {
        int c = i & 63;
        float v = fmaf(b2f(summed[i]), st2[c], st2[64 + c]);
        af[i] = f2b(spf(b2f(af[i]) + v));
    }
}

__global__ void k_pool(const u16* __restrict__ af, const int* __restrict__ cidx,
                       float* __restrict__ crysp) {
    int b = blockIdx.x;
    int ch = threadIdx.x & 63;
    int part = threadIdx.x >> 6;
    float acc = 0.f;
    for (int k = part; k < APC; k += 4) {
        int a = cidx[b * APC + k];
        acc += b2f(af[(long)a * 64 + ch]);
    }
    __shared__ float red[256];
    red[threadIdx.x] = acc;
    __syncthreads();
    if (part == 0) {
        float s = red[ch] + red[64 + ch] + red[128 + ch] + red[192 + ch];
        crysp[b * 64 + ch] = spf(s * (1.0f / APC));
    }
}

__global__ void k_head(const float* __restrict__ crysp, const void* __restrict__ Wfc,
                       const void* __restrict__ bfc, const void* __restrict__ Wout,
                       const void* __restrict__ bout, void* __restrict__ outv,
                       const int* __restrict__ flag) {
    int f = flag[0];
    int b = blockIdx.x;
    int t = threadIdx.x;  // 128
    __shared__ float cr[64];
    __shared__ float h[HF];
    if (t < 64) cr[t] = crysp[b * 64 + t];
    __syncthreads();
    float acc = ldf(bfc, t, f);
    for (int k = 0; k < 64; ++k) acc = fmaf(cr[k], ldf(Wfc, (long)k * HF + t, f), acc);
    h[t] = spf(acc);
    __syncthreads();
    if (t < HID) {
        float o = ldf(bout, t, f);
        for (int k = 0; k < HF; ++k) o = fmaf(h[k], ldf(Wout, (long)k * HID + t, f), o);
        if (f) ((float*)outv)[b * HID + t] = o;
        else   ((u16*)outv)[b * HID + t] = f2b(o);
    }
}

extern "C" void kernel_launch(void* const* d_in, const int* in_sizes, int n_in,
                              void* d_out, int out_size, void* d_ws, size_t ws_size,
                              hipStream_t stream) {
    const int* atom_num = (const int*)d_in[0];
    const void* nbr_fea = d_in[1];
    const int* nbr_idx  = (const int*)d_in[2];
    const int* cidx     = (const int*)d_in[3];
    const void* emb     = d_in[4];
    const void* W_full  = d_in[5];
    const void* b_full  = d_in[6];
    const void* bn1_g   = d_in[7];
    const void* bn1_b   = d_in[8];
    const void* bn2_g   = d_in[9];
    const void* bn2_b   = d_in[10];
    const void* W_fc    = d_in[11];
    const void* b_fc    = d_in[12];
    const void* W_out   = d_in[13];
    const void* b_out   = d_in[14];

    // ---- ws layout: control + staging first, big arrays after ----
    char* wsb = (char*)d_ws;
    int*   flag   = (int*)wsb;                          // 16 B
    float* stats1 = (float*)(wsb + 16);                 // 256
    float* st1    = stats1 + 256;                       // 256
    float* stats2 = st1 + 256;                          // 128
    float* st2    = stats2 + 128;                       // 128
    float* crysp  = st2 + 128;                          // 6400
    float* Wst    = crysp + 6400;                       // 21632
    float* bst    = Wst + 21632;                        // 128
    float* bn1s   = bst + 128;                          // 256
    float* bn2s   = bn1s + 256;                         // 128
    u16*   af     = (u16*)(bn2s + 128);                 // N*64 bf16 = 12.8 MB
    u16*   summed = af + (long)N_ATOM * 64;             // N*64 bf16 = 12.8 MB
    u16*   An     = summed + (long)N_ATOM * 64;         // N*128 bf16 = 25.6 MB
    char*  afterAn = (char*)(An + (long)N_ATOM * 128);
    float* Rf = (float*)afterAn;                        // N*128 fp32 = 51.2 MB (rf=1)
    u16*   Rh = (u16*)afterAn;                          // N*128 bf16 = 25.6 MB (rf=0)

    size_t off_afterAn = (size_t)(afterAn - wsb);
    size_t need_f2  = off_afterAn + (size_t)N_ATOM * 128 * 4;
    size_t need_f2h = off_afterAn + (size_t)N_ATOM * 128 * 2;
    size_t need_f1  = off_afterAn;
    int rf = (ws_size >= need_f2) ? 1 : ((ws_size >= need_f2h) ? 0 : -1);
    bool f1 = ws_size >= need_f1;

    k_probe<<<1, 256, 0, stream>>>((const u16*)nbr_fea, flag);
    k_embed<<<(N_ATOM * 64 + 255) / 256, 256, 0, stream>>>(atom_num, emb, af, flag);

    const long WROWS = (long)(2 * AF + NF) * 128;  // 21632
    for (int L = 0; L < NC; ++L) {
        hipMemsetAsync(stats1, 0, 768 * sizeof(float), stream);
        k_stage<<<(int)((WROWS + 128 + 255) / 256), 256, 0, stream>>>(
            W_full, (long)L * WROWS, b_full, (long)L * 128,
            bn1_g, bn1_b, bn2_g, bn2_b, (long)L,
            Wst, bst, bn1s, bn2s, flag);
        if (rf >= 0) {
            k_asn<<<N_ATOM / 4, 256, 0, stream>>>(af, Wst, bst, Rf, Rh, An, rf);
            k_conv<false, 0><<<2500, 256, 0, stream>>>(nbr_fea, nbr_idx, af, An,
                Wst, bst, nullptr, nullptr, stats1, flag, Rf, Rh, rf);
            k_bn1<<<1, 128, 0, stream>>>(stats1, bn1s, st1);
            k_conv<true, 0><<<2500, 256, 0, stream>>>(nbr_fea, nbr_idx, af, An,
                Wst, bst, st1, summed, stats2, flag, Rf, Rh, rf);
        } else if (f1) {
            k_an<<<N_ATOM / 4, 256, 0, stream>>>(af, Wst, An);
            k_conv<false, 1><<<2500, 256, 0, stream>>>(nbr_fea, nbr_idx, af, An,
                Wst, bst, nullptr, nullptr, stats1, flag, nullptr, nullptr, 0);
            k_bn1<<<1, 128, 0, stream>>>(stats1, bn1s, st1);
            k_conv<true, 1><<<2500, 256, 0, stream>>>(nbr_fea, nbr_idx, af, An,
                Wst, bst, st1, summed, stats2, flag, nullptr, nullptr, 0);
        } else {
            k_conv<false, 2><<<2500, 256, 0, stream>>>(nbr_fea, nbr_idx, af, nullptr,
                Wst, bst, nullptr, nullptr, stats1, flag, nullptr, nullptr, 0);
            k_bn1<<<1, 128, 0, stream>>>(stats1, bn1s, st1);
            k_conv<true, 2><<<2500, 256, 0, stream>>>(nbr_fea, nbr_idx, af, nullptr,
                Wst, bst, st1, summed, stats2, flag, nullptr, nullptr, 0);
        }
        k_bn2<<<1, 64, 0, stream>>>(stats2, bn2s, st2);
        k_update<<<(N_ATOM * 64 + 255) / 256, 256, 0, stream>>>(af, summed, st2);
    }
    k_pool<<<N0C, 256, 0, stream>>>(af, cidx, crysp);
    k_head<<<N0C, HF, 0, stream>>>(crysp, W_fc, b_fc, W_out, b_out, d_out, flag);
}

// Round 3
// 3760.946 us; speedup vs baseline: 1.7676x; 1.0613x over previous
//
#include <hip/hip_runtime.h>

#define N_ATOM 100000
#define M_NBR  12
#define NF     41
#define AF     64
#define NC     3
#define N0C    100
#define APC    1000
#define HF     128
#define HID    64
#define EPS    1e-5f

typedef unsigned short u16;
typedef unsigned int   u32;

__device__ __forceinline__ float b2f(u16 u) {
    return __uint_as_float(((u32)u) << 16);
}
__device__ __forceinline__ u16 f2b(float f) {
    u32 x = __float_as_uint(f);
    u32 r = x + 0x7fffu + ((x >> 16) & 1u);
    return (u16)(r >> 16);
}
// dtype-flexible load: f==1 -> buffer is float32, else bf16
__device__ __forceinline__ float ldf(const void* p, long i, int f) {
    if (f) return ((const float*)p)[i];
    return b2f(((const u16*)p)[i]);
}
__device__ __forceinline__ float spf(float x) {           // softplus, stable
    return fmaxf(x, 0.0f) + log1pf(expf(-fabsf(x)));
}
__device__ __forceinline__ float sigf(float x) {
    return 1.0f / (1.0f + expf(-x));
}
// guaranteed v_readlane broadcast (uniform lane, SGPR result, no ds_bpermute)
__device__ __forceinline__ float rdl(float v, int l) {
    return __uint_as_float((u32)__builtin_amdgcn_readlane(__float_as_uint(v), l));
}

// ---- dtype probe: decode first 8192 u16 of nbr_fea as bf16; count implausible ----
__global__ void k_probe(const u16* __restrict__ nf, int* __restrict__ flag) {
    int t = threadIdx.x;  // 256
    int bad = 0;
    for (int i = t; i < 8192; i += 256) {
        u16 u = nf[i];
        float v = b2f(u);
        float a = fabsf(v);
        if (!(a <= 1024.0f) || (((u & 0x7fffu) != 0) && a < 1e-10f)) bad++;
    }
    __shared__ int cnt;
    if (t == 0) cnt = 0;
    __syncthreads();
    atomicAdd(&cnt, bad);
    __syncthreads();
    if (t == 0) flag[0] = (cnt > 800) ? 1 : 0;
}

// ---- stage layer params into fp32 ws buffers (dtype-agnostic downstream) ----
__global__ void k_stage(const void* __restrict__ W, long Woff,
                        const void* __restrict__ b, long boff,
                        const void* __restrict__ g1, const void* __restrict__ b1,
                        const void* __restrict__ g2, const void* __restrict__ b2, long L,
                        float* __restrict__ Wst, float* __restrict__ bst,
                        float* __restrict__ bn1s, float* __restrict__ bn2s,
                        const int* __restrict__ flag) {
    int f = flag[0];
    long i = (long)blockIdx.x * 256 + threadIdx.x;
    const long NW_ = (long)(2 * AF + NF) * 128;  // 21632
    if (i < NW_) {
        Wst[i] = ldf(W, Woff + i, f);
    } else if (i < NW_ + 128) {
        long c = i - NW_;
        bst[c] = ldf(b, boff + c, f);
        bn1s[c] = ldf(g1, L * 128 + c, f);
        bn1s[128 + c] = ldf(b1, L * 128 + c, f);
        if (c < 64) {
            bn2s[c] = ldf(g2, L * 64 + c, f);
            bn2s[64 + c] = ldf(b2, L * 64 + c, f);
        }
    }
}

// ---- atom_fea = embedding[atom_num], stored bf16 in ws ----
__global__ void k_embed(const int* __restrict__ atom_num, const void* __restrict__ emb,
                        u16* __restrict__ af, const int* __restrict__ flag) {
    int f = flag[0];
    int i = blockIdx.x * 256 + threadIdx.x;
    if (i < N_ATOM * AF) {
        int n = i >> 6, c = i & 63;
        af[i] = f2b(ldf(emb, (long)atom_num[n] * AF + c, f));
    }
}

// ---- round-0 k_an (MODE=1 fallback): An = af @ W[64:128], unpacked layout ----
__global__ __launch_bounds__(256) void k_an(const u16* __restrict__ af,
                       const float* __restrict__ Wst, u16* __restrict__ An) {
    int wv = threadIdx.x >> 6;
    int lane = threadIdx.x & 63;
    int n = blockIdx.x * 4 + wv;
    float afv = b2f(af[n * AF + lane]);
    float a0 = 0.f, a1 = 0.f;
    for (int k = 0; k < AF; ++k) {
        float a = __shfl(afv, k, 64);
        a0 = fmaf(a, Wst[(AF + k) * 128 + lane], a0);
        a1 = fmaf(a, Wst[(AF + k) * 128 + 64 + lane], a1);
    }
    An[(long)n * 128 + lane] = f2b(a0);
    An[(long)n * 128 + 64 + lane] = f2b(a1);
}

// ---- MODE=0 precompute: R = af@W[0:64]+b (fp32 or bf16), An2 = af@W[64:128] (packed bf16) ----
// Accumulation order identical to prior rounds; broadcast via v_readlane (no ds_bpermute).
__global__ __launch_bounds__(256) void k_asn(const u16* __restrict__ af,
                       const float* __restrict__ Wst, const float* __restrict__ bst,
                       float* __restrict__ Rf, u16* __restrict__ Rh,
                       u16* __restrict__ An2, int rf) {
    int lane = threadIdx.x & 63;
    int n = blockIdx.x * 4 + (threadIdx.x >> 6);
    float afv = b2f(af[n * AF + lane]);
    float r0 = bst[lane], r1 = bst[64 + lane];
    float q0 = 0.f, q1 = 0.f;
    #pragma unroll 8
    for (int k = 0; k < AF; ++k) {
        float a = rdl(afv, k);
        r0 = fmaf(a, Wst[k * 128 + lane], r0);
        r1 = fmaf(a, Wst[k * 128 + 64 + lane], r1);
        q0 = fmaf(a, Wst[(AF + k) * 128 + lane], q0);
        q1 = fmaf(a, Wst[(AF + k) * 128 + 64 + lane], q1);
    }
    long p = (long)n * 64 + lane;
    if (rf) {
        *(float2*)(Rf + p * 2) = make_float2(r0, r1);
    } else {
        ((u32*)Rh)[p] = (u32)f2b(r0) | ((u32)f2b(r1) << 16);
    }
    ((u32*)An2)[p] = (u32)f2b(q0) | ((u32)f2b(q1) << 16);
}

// ---- conv sweep.
// MODE 0: R & An precomputed (packed); 2-edge unroll, readlane broadcast.
// MODE 1: round-0 fast (As in-kernel, An read, unpacked layout).
// MODE 2: round-0 slow (As + An in-kernel).
// APPLY=false -> bn1 stats; true -> apply bn1 + gate + summed + bn2 stats.
// NOTE: plain launch_bounds(256) — a (256,4) min-wave clamp forced VGPR=64 and
// spilled the 82-entry w0/w1 arrays to scratch (+300 MB WRITE_SIZE, R2 post-mortem).
template<bool APPLY, int MODE>
__global__ __launch_bounds__(256) void k_conv(const void* __restrict__ nbr_fea,
                       const int* __restrict__ nbr_idx,
                       const u16* __restrict__ af, const u16* __restrict__ An,
                       const float* __restrict__ Wst, const float* __restrict__ bst,
                       const float* __restrict__ st1,   // [0:128]=scale [128:256]=shift
                       u16* __restrict__ summed,
                       float* __restrict__ statsOut,
                       const int* __restrict__ flag,
                       const float* __restrict__ Rf, const u16* __restrict__ Rh, int rf) {
    int f = flag[0];
    int lane = threadIdx.x & 63;
    int wv = threadIdx.x >> 6;
    int gwave = blockIdx.x * 4 + wv;
    int NW = gridDim.x * 4;
    // register-resident W_edge columns {lane, lane+64}; rows 128..168
    float w0[NF], w1[NF];
    #pragma unroll
    for (int k = 0; k < NF; ++k) {
        w0[k] = Wst[(128 + k) * 128 + lane];
        w1[k] = Wst[(128 + k) * 128 + 64 + lane];
    }
    float s0 = 0.f, t0 = 0.f, s1 = 0.f, t1 = 0.f;
    if (APPLY) {
        s0 = st1[lane];        s1 = st1[lane + 64];
        t0 = st1[128 + lane];  t1 = st1[192 + lane];
    }
    float sum0 = 0.f, ssq0 = 0.f, sum1 = 0.f, ssq1 = 0.f;

    if (MODE == 0) {
        for (int n = gwave; n < N_ATOM; n += NW) {
            long p = (long)n * 64 + lane;
            float r0, r1;
            if (rf) {
                float2 rr = *(const float2*)(Rf + p * 2);
                r0 = rr.x; r1 = rr.y;
            } else {
                u32 rr = ((const u32*)Rh)[p];
                r0 = b2f((u16)(rr & 0xffffu)); r1 = b2f((u16)(rr >> 16));
            }
            float asum = 0.f;
            for (int m = 0; m < M_NBR; m += 2) {
                long ra = (long)n * M_NBR + m;
                int2 jj = *(const int2*)(nbr_idx + ra);
                float nv0, nv1;
                if (f) {
                    const float* np = (const float*)nbr_fea + ra * NF;
                    nv0 = (lane < NF) ? np[lane] : 0.f;
                    nv1 = (lane < NF) ? np[NF + lane] : 0.f;
                } else {
                    const u16* np = (const u16*)nbr_fea + ra * NF;
                    nv0 = (lane < NF) ? b2f(np[lane]) : 0.f;
                    nv1 = (lane < NF) ? b2f(np[NF + lane]) : 0.f;
                }
                u32 qa = ((const u32*)An)[(long)jj.x * 64 + lane];
                u32 qb = ((const u32*)An)[(long)jj.y * 64 + lane];
                float ea0 = r0, ea1 = r1, eb0 = r0, eb1 = r1;
                #pragma unroll
                for (int k = 0; k < NF; ++k) {
                    float va = rdl(nv0, k);
                    float vb = rdl(nv1, k);
                    ea0 = fmaf(va, w0[k], ea0);
                    ea1 = fmaf(va, w1[k], ea1);
                    eb0 = fmaf(vb, w0[k], eb0);
                    eb1 = fmaf(vb, w1[k], eb1);
                }
                float ga0 = ea0 + b2f((u16)(qa & 0xffffu));
                float ga1 = ea1 + b2f((u16)(qa >> 16));
                float gb0 = eb0 + b2f((u16)(qb & 0xffffu));
                float gb1 = eb1 + b2f((u16)(qb >> 16));
                if (APPLY) {
                    asum += sigf(fmaf(ga0, s0, t0)) * spf(fmaf(ga1, s1, t1));
                    asum += sigf(fmaf(gb0, s0, t0)) * spf(fmaf(gb1, s1, t1));
                } else {
                    sum0 += ga0 + gb0; ssq0 += ga0 * ga0 + gb0 * gb0;
                    sum1 += ga1 + gb1; ssq1 += ga1 * ga1 + gb1 * gb1;
                }
            }
            if (APPLY) {
                summed[p] = f2b(asum);
                sum0 += asum; ssq0 += asum * asum;
            }
        }
    } else {
        float b0 = bst[lane];
        float b1 = bst[64 + lane];
        for (int n = gwave; n < N_ATOM; n += NW) {
            // As = af[n] @ W[0:64] + b
            float afv = b2f(af[n * AF + lane]);
            float as0 = b0, as1 = b1;
            for (int k = 0; k < AF; ++k) {
                float a = __shfl(afv, k, 64);
                as0 = fmaf(a, Wst[k * 128 + lane], as0);
                as1 = fmaf(a, Wst[k * 128 + 64 + lane], as1);
            }
            float asum = 0.f;
            for (int m = 0; m < M_NBR; ++m) {
                long r = (long)n * M_NBR + m;
                int j = nbr_idx[r];
                float nv = (lane < NF) ? ldf(nbr_fea, r * NF + lane, f) : 0.f;
                float e0 = as0, e1 = as1;
                #pragma unroll
                for (int k = 0; k < NF; ++k) {
                    float v = __shfl(nv, k, 64);
                    e0 = fmaf(v, w0[k], e0);
                    e1 = fmaf(v, w1[k], e1);
                }
                float g0, g1;
                if (MODE == 2) {
                    float aj = b2f(af[(long)j * AF + lane]);
                    float an0 = 0.f, an1 = 0.f;
                    for (int k = 0; k < AF; ++k) {
                        float a = __shfl(aj, k, 64);
                        an0 = fmaf(a, Wst[(AF + k) * 128 + lane], an0);
                        an1 = fmaf(a, Wst[(AF + k) * 128 + 64 + lane], an1);
                    }
                    g0 = e0 + an0; g1 = e1 + an1;
                } else {
                    g0 = e0 + b2f(An[(long)j * 128 + lane]);
                    g1 = e1 + b2f(An[(long)j * 128 + 64 + lane]);
                }
                if (APPLY) {
                    float ft = sigf(fmaf(g0, s0, t0));
                    float cc = spf(fmaf(g1, s1, t1));
                    asum += ft * cc;
                } else {
                    sum0 += g0; ssq0 += g0 * g0;
                    sum1 += g1; ssq1 += g1 * g1;
                }
            }
            if (APPLY) {
                summed[(long)n * 64 + lane] = f2b(asum);
                sum0 += asum; ssq0 += asum * asum;
            }
        }
    }

    __shared__ float red[256];
    if (APPLY) {
        if (threadIdx.x < 128) red[threadIdx.x] = 0.f;
        __syncthreads();
        atomicAdd(&red[lane], sum0);
        atomicAdd(&red[64 + lane], ssq0);
        __syncthreads();
        if (threadIdx.x < 128) atomicAdd(&statsOut[threadIdx.x], red[threadIdx.x]);
    } else {
        red[threadIdx.x] = 0.f;
        __syncthreads();
        atomicAdd(&red[lane], sum0);
        atomicAdd(&red[64 + lane], sum1);
        atomicAdd(&red[128 + lane], ssq0);
        atomicAdd(&red[192 + lane], ssq1);
        __syncthreads();
        atomicAdd(&statsOut[threadIdx.x], red[threadIdx.x]);
    }
}

__global__ void k_bn1(const float* __restrict__ stats, const float* __restrict__ bn1s,
                      float* __restrict__ st) {
    int c = threadIdx.x;  // 128
    float cnt = (float)N_ATOM * (float)M_NBR;
    float mu = stats[c] / cnt;
    float var = fmaxf(stats[128 + c] / cnt - mu * mu, 0.0f);
    float s = bn1s[c] * rsqrtf(var + EPS);
    st[c] = s;
    st[128 + c] = bn1s[128 + c] - mu * s;
}

__global__ void k_bn2(const float* __restrict__ stats, const float* __restrict__ bn2s,
                      float* __restrict__ st) {
    int c = threadIdx.x;  // 64
    float cnt = (float)N_ATOM;
    float mu = stats[c] / cnt;
    float var = fmaxf(stats[64 + c] / cnt - mu * mu, 0.0f);
    float s = bn2s[c] * rsqrtf(var + EPS);
    st[c] = s;
    st[64 + c] = bn2s[64 + c] - mu * s;
}

__global__ void k_update(u16* __restrict__ af, const u16* __restrict__ summed,
                         const float* __restrict__ st2) {
    int i = blockIdx.x * 256 + threadIdx.x;
    if (i < N_ATOM * 64) {
        int c = i & 63;
        float v = fmaf(b2f(summed[i]), st2[c], st2[64 + c]);
        af[i] = f2b(spf(b2f(af[i]) + v));
    }
}

__global__ void k_pool(const u16* __restrict__ af, const int* __restrict__ cidx,
                       float* __restrict__ crysp) {
    int b = blockIdx.x;
    int ch = threadIdx.x & 63;
    int part = threadIdx.x >> 6;
    float acc = 0.f;
    for (int k = part; k < APC; k += 4) {
        int a = cidx[b * APC + k];
        acc += b2f(af[(long)a * 64 + ch]);
    }
    __shared__ float red[256];
    red[threadIdx.x] = acc;
    __syncthreads();
    if (part == 0) {
        float s = red[ch] + red[64 + ch] + red[128 + ch] + red[192 + ch];
        crysp[b * 64 + ch] = spf(s * (1.0f / APC));
    }
}

__global__ void k_head(const float* __restrict__ crysp, const void* __restrict__ Wfc,
                       const void* __restrict__ bfc, const void* __restrict__ Wout,
                       const void* __restrict__ bout, void* __restrict__ outv,
                       const int* __restrict__ flag) {
    int f = flag[0];
    int b = blockIdx.x;
    int t = threadIdx.x;  // 128
    __shared__ float cr[64];
    __shared__ float h[HF];
    if (t < 64) cr[t] = crysp[b * 64 + t];
    __syncthreads();
    float acc = ldf(bfc, t, f);
    for (int k = 0; k < 64; ++k) acc = fmaf(cr[k], ldf(Wfc, (long)k * HF + t, f), acc);
    h[t] = spf(acc);
    __syncthreads();
    if (t < HID) {
        float o = ldf(bout, t, f);
        for (int k = 0; k < HF; ++k) o = fmaf(h[k], ldf(Wout, (long)k * HID + t, f), o);
        if (f) ((float*)outv)[b * HID + t] = o;
        else   ((u16*)outv)[b * HID + t] = f2b(o);
    }
}

extern "C" void kernel_launch(void* const* d_in, const int* in_sizes, int n_in,
                              void* d_out, int out_size, void* d_ws, size_t ws_size,
                              hipStream_t stream) {
    const int* atom_num = (const int*)d_in[0];
    const void* nbr_fea = d_in[1];
    const int* nbr_idx  = (const int*)d_in[2];
    const int* cidx     = (const int*)d_in[3];
    const void* emb     = d_in[4];
    const void* W_full  = d_in[5];
    const void* b_full  = d_in[6];
    const void* bn1_g   = d_in[7];
    const void* bn1_b   = d_in[8];
    const void* bn2_g   = d_in[9];
    const void* bn2_b   = d_in[10];
    const void* W_fc    = d_in[11];
    const void* b_fc    = d_in[12];
    const void* W_out   = d_in[13];
    const void* b_out   = d_in[14];

    // ---- ws layout: control + staging first, big arrays after ----
    char* wsb = (char*)d_ws;
    int*   flag   = (int*)wsb;                          // 16 B
    float* stats1 = (float*)(wsb + 16);                 // 256
    float* st1    = stats1 + 256;                       // 256
    float* stats2 = st1 + 256;                          // 128
    float* st2    = stats2 + 128;                       // 128
    float* crysp  = st2 + 128;                          // 6400
    float* Wst    = crysp + 6400;                       // 21632
    float* bst    = Wst + 21632;                        // 128
    float* bn1s   = bst + 128;                          // 256
    float* bn2s   = bn1s + 256;                         // 128
    u16*   af     = (u16*)(bn2s + 128);                 // N*64 bf16 = 12.8 MB
    u16*   summed = af + (long)N_ATOM * 64;             // N*64 bf16 = 12.8 MB
    u16*   An     = summed + (long)N_ATOM * 64;         // N*128 bf16 = 25.6 MB
    char*  afterAn = (char*)(An + (long)N_ATOM * 128);
    float* Rf = (float*)afterAn;                        // N*128 fp32 = 51.2 MB (rf=1)
    u16*   Rh = (u16*)afterAn;                          // N*128 bf16 = 25.6 MB (rf=0)

    size_t off_afterAn = (size_t)(afterAn - wsb);
    size_t need_f2  = off_afterAn + (size_t)N_ATOM * 128 * 4;
    size_t need_f2h = off_afterAn + (size_t)N_ATOM * 128 * 2;
    size_t need_f1  = off_afterAn;
    int rf = (ws_size >= need_f2) ? 1 : ((ws_size >= need_f2h) ? 0 : -1);
    bool f1 = ws_size >= need_f1;

    k_probe<<<1, 256, 0, stream>>>((const u16*)nbr_fea, flag);
    k_embed<<<(N_ATOM * 64 + 255) / 256, 256, 0, stream>>>(atom_num, emb, af, flag);

    const long WROWS = (long)(2 * AF + NF) * 128;  // 21632
    for (int L = 0; L < NC; ++L) {
        hipMemsetAsync(stats1, 0, 768 * sizeof(float), stream);
        k_stage<<<(int)((WROWS + 128 + 255) / 256), 256, 0, stream>>>(
            W_full, (long)L * WROWS, b_full, (long)L * 128,
            bn1_g, bn1_b, bn2_g, bn2_b, (long)L,
            Wst, bst, bn1s, bn2s, flag);
        if (rf >= 0) {
            k_asn<<<N_ATOM / 4, 256, 0, stream>>>(af, Wst, bst, Rf, Rh, An, rf);
            k_conv<false, 0><<<2500, 256, 0, stream>>>(nbr_fea, nbr_idx, af, An,
                Wst, bst, nullptr, nullptr, stats1, flag, Rf, Rh, rf);
            k_bn1<<<1, 128, 0, stream>>>(stats1, bn1s, st1);
            k_conv<true, 0><<<2500, 256, 0, stream>>>(nbr_fea, nbr_idx, af, An,
                Wst, bst, st1, summed, stats2, flag, Rf, Rh, rf);
        } else if (f1) {
            k_an<<<N_ATOM / 4, 256, 0, stream>>>(af, Wst, An);
            k_conv<false, 1><<<2500, 256, 0, stream>>>(nbr_fea, nbr_idx, af, An,
                Wst, bst, nullptr, nullptr, stats1, flag, nullptr, nullptr, 0);
            k_bn1<<<1, 128, 0, stream>>>(stats1, bn1s, st1);
            k_conv<true, 1><<<2500, 256, 0, stream>>>(nbr_fea, nbr_idx, af, An,
                Wst, bst, st1, summed, stats2, flag, nullptr, nullptr, 0);
        } else {
            k_conv<false, 2><<<2500, 256, 0, stream>>>(nbr_fea, nbr_idx, af, nullptr,
                Wst, bst, nullptr, nullptr, stats1, flag, nullptr, nullptr, 0);
            k_bn1<<<1, 128, 0, stream>>>(stats1, bn1s, st1);
            k_conv<true, 2><<<2500, 256, 0, stream>>>(nbr_fea, nbr_idx, af, nullptr,
                Wst, bst, st1, summed, stats2, flag, nullptr, nullptr, 0);
        }
        k_bn2<<<1, 64, 0, stream>>>(stats2, bn2s, st2);
        k_update<<<(N_ATOM * 64 + 255) / 256, 256, 0, stream>>>(af, summed, st2);
    }
    k_pool<<<N0C, 256, 0, stream>>>(af, cidx, crysp);
    k_head<<<N0C, HF, 0, stream>>>(crysp, W_fc, b_fc, W_out, b_out, d_out, flag);
}

// Round 4
// 3747.294 us; speedup vs baseline: 1.7740x; 1.0036x over previous
//
#include <hip/hip_runtime.h>

#define N_ATOM 100000
#define M_NBR  12
#define NF     41
#define AF     64
#define NC     3
#define N0C    100
#define APC    1000
#define HF     128
#define HID    64
#define EPS    1e-5f

typedef unsigned short u16;
typedef unsigned int   u32;

__device__ __forceinline__ float b2f(u16 u) {
    return __uint_as_float(((u32)u) << 16);
}
__device__ __forceinline__ u16 f2b(float f) {
    u32 x = __float_as_uint(f);
    u32 r = x + 0x7fffu + ((x >> 16) & 1u);
    return (u16)(r >> 16);
}
// dtype-flexible load: f==1 -> buffer is float32, else bf16
__device__ __forceinline__ float ldf(const void* p, long i, int f) {
    if (f) return ((const float*)p)[i];
    return b2f(((const u16*)p)[i]);
}
__device__ __forceinline__ float spf(float x) {           // softplus, stable
    return fmaxf(x, 0.0f) + log1pf(expf(-fabsf(x)));
}
__device__ __forceinline__ float sigf(float x) {
    return 1.0f / (1.0f + expf(-x));
}
// guaranteed v_readlane broadcast (uniform lane, SGPR result, no ds_bpermute)
__device__ __forceinline__ float rdl(float v, int l) {
    return __uint_as_float((u32)__builtin_amdgcn_readlane(__float_as_uint(v), l));
}

// ---- dtype probe: decode first 8192 u16 of nbr_fea as bf16; count implausible ----
__global__ void k_probe(const u16* __restrict__ nf, int* __restrict__ flag) {
    int t = threadIdx.x;  // 256
    int bad = 0;
    for (int i = t; i < 8192; i += 256) {
        u16 u = nf[i];
        float v = b2f(u);
        float a = fabsf(v);
        if (!(a <= 1024.0f) || (((u & 0x7fffu) != 0) && a < 1e-10f)) bad++;
    }
    __shared__ int cnt;
    if (t == 0) cnt = 0;
    __syncthreads();
    atomicAdd(&cnt, bad);
    __syncthreads();
    if (t == 0) flag[0] = (cnt > 800) ? 1 : 0;
}

// ---- stage layer params into fp32 ws buffers (dtype-agnostic downstream) ----
__global__ void k_stage(const void* __restrict__ W, long Woff,
                        const void* __restrict__ b, long boff,
                        const void* __restrict__ g1, const void* __restrict__ b1,
                        const void* __restrict__ g2, const void* __restrict__ b2, long L,
                        float* __restrict__ Wst, float* __restrict__ bst,
                        float* __restrict__ bn1s, float* __restrict__ bn2s,
                        const int* __restrict__ flag) {
    int f = flag[0];
    long i = (long)blockIdx.x * 256 + threadIdx.x;
    const long NW_ = (long)(2 * AF + NF) * 128;  // 21632
    if (i < NW_) {
        Wst[i] = ldf(W, Woff + i, f);
    } else if (i < NW_ + 128) {
        long c = i - NW_;
        bst[c] = ldf(b, boff + c, f);
        bn1s[c] = ldf(g1, L * 128 + c, f);
        bn1s[128 + c] = ldf(b1, L * 128 + c, f);
        if (c < 64) {
            bn2s[c] = ldf(g2, L * 64 + c, f);
            bn2s[64 + c] = ldf(b2, L * 64 + c, f);
        }
    }
}

// ---- atom_fea = embedding[atom_num], stored bf16 in ws ----
__global__ void k_embed(const int* __restrict__ atom_num, const void* __restrict__ emb,
                        u16* __restrict__ af, const int* __restrict__ flag) {
    int f = flag[0];
    int i = blockIdx.x * 256 + threadIdx.x;
    if (i < N_ATOM * AF) {
        int n = i >> 6, c = i & 63;
        af[i] = f2b(ldf(emb, (long)atom_num[n] * AF + c, f));
    }
}

// ---- round-0 k_an (MODE=1 fallback): An = af @ W[64:128], unpacked layout ----
__global__ __launch_bounds__(256) void k_an(const u16* __restrict__ af,
                       const float* __restrict__ Wst, u16* __restrict__ An) {
    int wv = threadIdx.x >> 6;
    int lane = threadIdx.x & 63;
    int n = blockIdx.x * 4 + wv;
    float afv = b2f(af[n * AF + lane]);
    float a0 = 0.f, a1 = 0.f;
    for (int k = 0; k < AF; ++k) {
        float a = __shfl(afv, k, 64);
        a0 = fmaf(a, Wst[(AF + k) * 128 + lane], a0);
        a1 = fmaf(a, Wst[(AF + k) * 128 + 64 + lane], a1);
    }
    An[(long)n * 128 + lane] = f2b(a0);
    An[(long)n * 128 + 64 + lane] = f2b(a1);
}

// ---- MODE=0 precompute: R = af@W[0:64]+b (fp32 or bf16), An2 = af@W[64:128] (packed bf16) ----
// Accumulation order identical to prior rounds; broadcast via v_readlane (no ds_bpermute).
__global__ __launch_bounds__(256) void k_asn(const u16* __restrict__ af,
                       const float* __restrict__ Wst, const float* __restrict__ bst,
                       float* __restrict__ Rf, u16* __restrict__ Rh,
                       u16* __restrict__ An2, int rf) {
    int lane = threadIdx.x & 63;
    int n = blockIdx.x * 4 + (threadIdx.x >> 6);
    float afv = b2f(af[n * AF + lane]);
    float r0 = bst[lane], r1 = bst[64 + lane];
    float q0 = 0.f, q1 = 0.f;
    #pragma unroll 8
    for (int k = 0; k < AF; ++k) {
        float a = rdl(afv, k);
        r0 = fmaf(a, Wst[k * 128 + lane], r0);
        r1 = fmaf(a, Wst[k * 128 + 64 + lane], r1);
        q0 = fmaf(a, Wst[(AF + k) * 128 + lane], q0);
        q1 = fmaf(a, Wst[(AF + k) * 128 + 64 + lane], q1);
    }
    long p = (long)n * 64 + lane;
    if (rf) {
        *(float2*)(Rf + p * 2) = make_float2(r0, r1);
    } else {
        ((u32*)Rh)[p] = (u32)f2b(r0) | ((u32)f2b(r1) << 16);
    }
    ((u32*)An2)[p] = (u32)f2b(q0) | ((u32)f2b(q1) << 16);
}

// ---- conv sweep.
// MODE 0: R & An precomputed (packed); 2-edge unroll, readlane broadcast,
//         W_edge staged in LDS as float2[NF][64] (21 KB). Per-use cost = one
//         ds_read_b64 with a 16-bit immediate offset (k*512) — no address math,
//         no VGPR array pressure. (R3 post-mortem: VGPR=76 < the 82-float w0/w1
//         arrays, so the compiler re-loaded them from global Wst with 64-bit
//         addressing every use -> ~620 VALU instr/edge vs ~140 in source.)
// MODE 1: round-0 fast (As in-kernel, An read, unpacked layout).
// MODE 2: round-0 slow (As + An in-kernel).
// APPLY=false -> bn1 stats; true -> apply bn1 + gate + summed + bn2 stats.
// NOTE: plain launch_bounds(256) — a (256,4) min-wave clamp forced VGPR=64 and
// spilled the weight arrays to scratch (+300 MB WRITE_SIZE, R2 post-mortem).
template<bool APPLY, int MODE>
__global__ __launch_bounds__(256) void k_conv(const void* __restrict__ nbr_fea,
                       const int* __restrict__ nbr_idx,
                       const u16* __restrict__ af, const u16* __restrict__ An,
                       const float* __restrict__ Wst, const float* __restrict__ bst,
                       const float* __restrict__ st1,   // [0:128]=scale [128:256]=shift
                       u16* __restrict__ summed,
                       float* __restrict__ statsOut,
                       const int* __restrict__ flag,
                       const float* __restrict__ Rf, const u16* __restrict__ Rh, int rf) {
    int f = flag[0];
    int lane = threadIdx.x & 63;
    int wv = threadIdx.x >> 6;
    int gwave = blockIdx.x * 4 + wv;
    int NW = gridDim.x * 4;
    __shared__ float2 wlds[NF][64];   // 20992 B, MODE 0 only
    __shared__ float red[256];

    float s0 = 0.f, t0 = 0.f, s1 = 0.f, t1 = 0.f;
    if (APPLY) {
        s0 = st1[lane];        s1 = st1[lane + 64];
        t0 = st1[128 + lane];  t1 = st1[192 + lane];
    }
    float sum0 = 0.f, ssq0 = 0.f, sum1 = 0.f, ssq1 = 0.f;

    if (MODE == 0) {
        // stage W_edge rows 128..168, packed per out-channel pair (c, c+64)
        for (int i = threadIdx.x; i < NF * 64; i += 256) {
            int k = i >> 6, c = i & 63;
            wlds[k][c] = make_float2(Wst[(128 + k) * 128 + c],
                                     Wst[(128 + k) * 128 + 64 + c]);
        }
        __syncthreads();

        for (int n = gwave; n < N_ATOM; n += NW) {
            long p = (long)n * 64 + lane;
            float r0, r1;
            if (rf) {
                float2 rr = *(const float2*)(Rf + p * 2);
                r0 = rr.x; r1 = rr.y;
            } else {
                u32 rr = ((const u32*)Rh)[p];
                r0 = b2f((u16)(rr & 0xffffu)); r1 = b2f((u16)(rr >> 16));
            }
            float asum = 0.f;
            for (int m = 0; m < M_NBR; m += 2) {
                long ra = (long)n * M_NBR + m;
                int2 jj = *(const int2*)(nbr_idx + ra);
                float nv0, nv1;
                if (f) {
                    const float* np = (const float*)nbr_fea + ra * NF;
                    nv0 = (lane < NF) ? np[lane] : 0.f;
                    nv1 = (lane < NF) ? np[NF + lane] : 0.f;
                } else {
                    const u16* np = (const u16*)nbr_fea + ra * NF;
                    nv0 = (lane < NF) ? b2f(np[lane]) : 0.f;
                    nv1 = (lane < NF) ? b2f(np[NF + lane]) : 0.f;
                }
                u32 qa = ((const u32*)An)[(long)jj.x * 64 + lane];
                u32 qb = ((const u32*)An)[(long)jj.y * 64 + lane];
                float ea0 = r0, ea1 = r1, eb0 = r0, eb1 = r1;
                #pragma unroll
                for (int k = 0; k < NF; ++k) {
                    float2 w = wlds[k][lane];      // ds_read_b64, offset:k*512
                    float va = rdl(nv0, k);
                    float vb = rdl(nv1, k);
                    ea0 = fmaf(va, w.x, ea0);
                    ea1 = fmaf(va, w.y, ea1);
                    eb0 = fmaf(vb, w.x, eb0);
                    eb1 = fmaf(vb, w.y, eb1);
                }
                float ga0 = ea0 + b2f((u16)(qa & 0xffffu));
                float ga1 = ea1 + b2f((u16)(qa >> 16));
                float gb0 = eb0 + b2f((u16)(qb & 0xffffu));
                float gb1 = eb1 + b2f((u16)(qb >> 16));
                if (APPLY) {
                    asum += sigf(fmaf(ga0, s0, t0)) * spf(fmaf(ga1, s1, t1));
                    asum += sigf(fmaf(gb0, s0, t0)) * spf(fmaf(gb1, s1, t1));
                } else {
                    sum0 += ga0 + gb0; ssq0 += ga0 * ga0 + gb0 * gb0;
                    sum1 += ga1 + gb1; ssq1 += ga1 * ga1 + gb1 * gb1;
                }
            }
            if (APPLY) {
                summed[p] = f2b(asum);
                sum0 += asum; ssq0 += asum * asum;
            }
        }
    } else {
        // fallback paths (small-ws): register-array weights, shuffle broadcast
        float w0[NF], w1[NF];
        #pragma unroll
        for (int k = 0; k < NF; ++k) {
            w0[k] = Wst[(128 + k) * 128 + lane];
            w1[k] = Wst[(128 + k) * 128 + 64 + lane];
        }
        float b0 = bst[lane];
        float b1 = bst[64 + lane];
        for (int n = gwave; n < N_ATOM; n += NW) {
            // As = af[n] @ W[0:64] + b
            float afv = b2f(af[n * AF + lane]);
            float as0 = b0, as1 = b1;
            for (int k = 0; k < AF; ++k) {
                float a = __shfl(afv, k, 64);
                as0 = fmaf(a, Wst[k * 128 + lane], as0);
                as1 = fmaf(a, Wst[k * 128 + 64 + lane], as1);
            }
            float asum = 0.f;
            for (int m = 0; m < M_NBR; ++m) {
                long r = (long)n * M_NBR + m;
                int j = nbr_idx[r];
                float nv = (lane < NF) ? ldf(nbr_fea, r * NF + lane, f) : 0.f;
                float e0 = as0, e1 = as1;
                #pragma unroll
                for (int k = 0; k < NF; ++k) {
                    float v = __shfl(nv, k, 64);
                    e0 = fmaf(v, w0[k], e0);
                    e1 = fmaf(v, w1[k], e1);
                }
                float g0, g1;
                if (MODE == 2) {
                    float aj = b2f(af[(long)j * AF + lane]);
                    float an0 = 0.f, an1 = 0.f;
                    for (int k = 0; k < AF; ++k) {
                        float a = __shfl(aj, k, 64);
                        an0 = fmaf(a, Wst[(AF + k) * 128 + lane], an0);
                        an1 = fmaf(a, Wst[(AF + k) * 128 + 64 + lane], an1);
                    }
                    g0 = e0 + an0; g1 = e1 + an1;
                } else {
                    g0 = e0 + b2f(An[(long)j * 128 + lane]);
                    g1 = e1 + b2f(An[(long)j * 128 + 64 + lane]);
                }
                if (APPLY) {
                    float ft = sigf(fmaf(g0, s0, t0));
                    float cc = spf(fmaf(g1, s1, t1));
                    asum += ft * cc;
                } else {
                    sum0 += g0; ssq0 += g0 * g0;
                    sum1 += g1; ssq1 += g1 * g1;
                }
            }
            if (APPLY) {
                summed[(long)n * 64 + lane] = f2b(asum);
                sum0 += asum; ssq0 += asum * asum;
            }
        }
    }

    if (APPLY) {
        if (threadIdx.x < 128) red[threadIdx.x] = 0.f;
        __syncthreads();
        atomicAdd(&red[lane], sum0);
        atomicAdd(&red[64 + lane], ssq0);
        __syncthreads();
        if (threadIdx.x < 128) atomicAdd(&statsOut[threadIdx.x], red[threadIdx.x]);
    } else {
        red[threadIdx.x] = 0.f;
        __syncthreads();
        atomicAdd(&red[lane], sum0);
        atomicAdd(&red[64 + lane], sum1);
        atomicAdd(&red[128 + lane], ssq0);
        atomicAdd(&red[192 + lane], ssq1);
        __syncthreads();
        atomicAdd(&statsOut[threadIdx.x], red[threadIdx.x]);
    }
}

__global__ void k_bn1(const float* __restrict__ stats, const float* __restrict__ bn1s,
                      float* __restrict__ st) {
    int c = threadIdx.x;  // 128
    float cnt = (float)N_ATOM * (float)M_NBR;
    float mu = stats[c] / cnt;
    float var = fmaxf(stats[128 + c] / cnt - mu * mu, 0.0f);
    float s = bn1s[c] * rsqrtf(var + EPS);
    st[c] = s;
    st[128 + c] = bn1s[128 + c] - mu * s;
}

__global__ void k_bn2(const float* __restrict__ stats, const float* __restrict__ bn2s,
                      float* __restrict__ st) {
    int c = threadIdx.x;  // 64
    float cnt = (float)N_ATOM;
    float mu = stats[c] / cnt;
    float var = fmaxf(stats[64 + c] / cnt - mu * mu, 0.0f);
    float s = bn2s[c] * rsqrtf(var + EPS);
    st[c] = s;
    st[64 + c] = bn2s[64 + c] - mu * s;
}

__global__ void k_update(u16* __restrict__ af, const u16* __restrict__ summed,
                         const float* __restrict__ st2) {
    int i = blockIdx.x * 256 + threadIdx.x;
    if (i < N_ATOM * 64) {
        int c = i & 63;
        float v = fmaf(b2f(summed[i]), st2[c], st2[64 + c]);
        af[i] = f2b(spf(b2f(af[i]) + v));
    }
}

__global__ void k_pool(const u16* __restrict__ af, const int* __restrict__ cidx,
                       float* __restrict__ crysp) {
    int b = blockIdx.x;
    int ch = threadIdx.x & 63;
    int part = threadIdx.x >> 6;
    float acc = 0.f;
    for (int k = part; k < APC; k += 4) {
        int a = cidx[b * APC + k];
        acc += b2f(af[(long)a * 64 + ch]);
    }
    __shared__ float red[256];
    red[threadIdx.x] = acc;
    __syncthreads();
    if (part == 0) {
        float s = red[ch] + red[64 + ch] + red[128 + ch] + red[192 + ch];
        crysp[b * 64 + ch] = spf(s * (1.0f / APC));
    }
}

__global__ void k_head(const float* __restrict__ crysp, const void* __restrict__ Wfc,
                       const void* __restrict__ bfc, const void* __restrict__ Wout,
                       const void* __restrict__ bout, void* __restrict__ outv,
                       const int* __restrict__ flag) {
    int f = flag[0];
    int b = blockIdx.x;
    int t = threadIdx.x;  // 128
    __shared__ float cr[64];
    __shared__ float h[HF];
    if (t < 64) cr[t] = crysp[b * 64 + t];
    __syncthreads();
    float acc = ldf(bfc, t, f);
    for (int k = 0; k < 64; ++k) acc = fmaf(cr[k], ldf(Wfc, (long)k * HF + t, f), acc);
    h[t] = spf(acc);
    __syncthreads();
    if (t < HID) {
        float o = ldf(bout, t, f);
        for (int k = 0; k < HF; ++k) o = fmaf(h[k], ldf(Wout, (long)k * HID + t, f), o);
        if (f) ((float*)outv)[b * HID + t] = o;
        else   ((u16*)outv)[b * HID + t] = f2b(o);
    }
}

extern "C" void kernel_launch(void* const* d_in, const int* in_sizes, int n_in,
                              void* d_out, int out_size, void* d_ws, size_t ws_size,
                              hipStream_t stream) {
    const int* atom_num = (const int*)d_in[0];
    const void* nbr_fea = d_in[1];
    const int* nbr_idx  = (const int*)d_in[2];
    const int* cidx     = (const int*)d_in[3];
    const void* emb     = d_in[4];
    const void* W_full  = d_in[5];
    const void* b_full  = d_in[6];
    const void* bn1_g   = d_in[7];
    const void* bn1_b   = d_in[8];
    const void* bn2_g   = d_in[9];
    const void* bn2_b   = d_in[10];
    const void* W_fc    = d_in[11];
    const void* b_fc    = d_in[12];
    const void* W_out   = d_in[13];
    const void* b_out   = d_in[14];

    // ---- ws layout: control + staging first, big arrays after ----
    char* wsb = (char*)d_ws;
    int*   flag   = (int*)wsb;                          // 16 B
    float* stats1 = (float*)(wsb + 16);                 // 256
    float* st1    = stats1 + 256;                       // 256
    float* stats2 = st1 + 256;                          // 128
    float* st2    = stats2 + 128;                       // 128
    float* crysp  = st2 + 128;                          // 6400
    float* Wst    = crysp + 6400;                       // 21632
    float* bst    = Wst + 21632;                        // 128
    float* bn1s   = bst + 128;                          // 256
    float* bn2s   = bn1s + 256;                         // 128
    u16*   af     = (u16*)(bn2s + 128);                 // N*64 bf16 = 12.8 MB
    u16*   summed = af + (long)N_ATOM * 64;             // N*64 bf16 = 12.8 MB
    u16*   An     = summed + (long)N_ATOM * 64;         // N*128 bf16 = 25.6 MB
    char*  afterAn = (char*)(An + (long)N_ATOM * 128);
    float* Rf = (float*)afterAn;                        // N*128 fp32 = 51.2 MB (rf=1)
    u16*   Rh = (u16*)afterAn;                          // N*128 bf16 = 25.6 MB (rf=0)

    size_t off_afterAn = (size_t)(afterAn - wsb);
    size_t need_f2  = off_afterAn + (size_t)N_ATOM * 128 * 4;
    size_t need_f2h = off_afterAn + (size_t)N_ATOM * 128 * 2;
    size_t need_f1  = off_afterAn;
    int rf = (ws_size >= need_f2) ? 1 : ((ws_size >= need_f2h) ? 0 : -1);
    bool f1 = ws_size >= need_f1;

    k_probe<<<1, 256, 0, stream>>>((const u16*)nbr_fea, flag);
    k_embed<<<(N_ATOM * 64 + 255) / 256, 256, 0, stream>>>(atom_num, emb, af, flag);

    const long WROWS = (long)(2 * AF + NF) * 128;  // 21632
    for (int L = 0; L < NC; ++L) {
        hipMemsetAsync(stats1, 0, 768 * sizeof(float), stream);
        k_stage<<<(int)((WROWS + 128 + 255) / 256), 256, 0, stream>>>(
            W_full, (long)L * WROWS, b_full, (long)L * 128,
            bn1_g, bn1_b, bn2_g, bn2_b, (long)L,
            Wst, bst, bn1s, bn2s, flag);
        if (rf >= 0) {
            k_asn<<<N_ATOM / 4, 256, 0, stream>>>(af, Wst, bst, Rf, Rh, An, rf);
            k_conv<false, 0><<<2500, 256, 0, stream>>>(nbr_fea, nbr_idx, af, An,
                Wst, bst, nullptr, nullptr, stats1, flag, Rf, Rh, rf);
            k_bn1<<<1, 128, 0, stream>>>(stats1, bn1s, st1);
            k_conv<true, 0><<<2500, 256, 0, stream>>>(nbr_fea, nbr_idx, af, An,
                Wst, bst, st1, summed, stats2, flag, Rf, Rh, rf);
        } else if (f1) {
            k_an<<<N_ATOM / 4, 256, 0, stream>>>(af, Wst, An);
            k_conv<false, 1><<<2500, 256, 0, stream>>>(nbr_fea, nbr_idx, af, An,
                Wst, bst, nullptr, nullptr, stats1, flag, nullptr, nullptr, 0);
            k_bn1<<<1, 128, 0, stream>>>(stats1, bn1s, st1);
            k_conv<true, 1><<<2500, 256, 0, stream>>>(nbr_fea, nbr_idx, af, An,
                Wst, bst, st1, summed, stats2, flag, nullptr, nullptr, 0);
        } else {
            k_conv<false, 2><<<2500, 256, 0, stream>>>(nbr_fea, nbr_idx, af, nullptr,
                Wst, bst, nullptr, nullptr, stats1, flag, nullptr, nullptr, 0);
            k_bn1<<<1, 128, 0, stream>>>(stats1, bn1s, st1);
            k_conv<true, 2><<<2500, 256, 0, stream>>>(nbr_fea, nbr_idx, af, nullptr,
                Wst, bst, st1, summed, stats2, flag, nullptr, nullptr, 0);
        }
        k_bn2<<<1, 64, 0, stream>>>(stats2, bn2s, st2);
        k_update<<<(N_ATOM * 64 + 255) / 256, 256, 0, stream>>>(af, summed, st2);
    }
    k_pool<<<N0C, 256, 0, stream>>>(af, cidx, crysp);
    k_head<<<N0C, HF, 0, stream>>>(crysp, W_fc, b_fc, W_out, b_out, d_out, flag);
}

// Round 5
// 3693.941 us; speedup vs baseline: 1.7996x; 1.0144x over previous
//
#include <hip/hip_runtime.h>
#include <hip/hip_fp16.h>

#define N_ATOM 100000
#define M_NBR  12
#define NF     41
#define AF     64
#define NC     3
#define N0C    100
#define APC    1000
#define HF     128
#define HID    64
#define EPS    1e-5f

typedef unsigned short u16;
typedef unsigned int   u32;

__device__ __forceinline__ float b2f(u16 u) {
    return __uint_as_float(((u32)u) << 16);
}
__device__ __forceinline__ u16 f2b(float f) {
    u32 x = __float_as_uint(f);
    u32 r = x + 0x7fffu + ((x >> 16) & 1u);
    return (u16)(r >> 16);
}
// dtype-flexible load: f==1 -> buffer is float32, else bf16
__device__ __forceinline__ float ldf(const void* p, long i, int f) {
    if (f) return ((const float*)p)[i];
    return b2f(((const u16*)p)[i]);
}
__device__ __forceinline__ float spf(float x) {           // softplus, stable
    return fmaxf(x, 0.0f) + log1pf(expf(-fabsf(x)));
}
__device__ __forceinline__ float sigf(float x) {
    return 1.0f / (1.0f + expf(-x));
}
// guaranteed v_readlane broadcast (uniform lane, SGPR result, no ds_bpermute)
__device__ __forceinline__ float rdl(float v, int l) {
    return __uint_as_float((u32)__builtin_amdgcn_readlane(__float_as_uint(v), l));
}

// ---- dtype probe: decode first 8192 u16 of nbr_fea as bf16; count implausible ----
__global__ void k_probe(const u16* __restrict__ nf, int* __restrict__ flag) {
    int t = threadIdx.x;  // 256
    int bad = 0;
    for (int i = t; i < 8192; i += 256) {
        u16 u = nf[i];
        float v = b2f(u);
        float a = fabsf(v);
        if (!(a <= 1024.0f) || (((u & 0x7fffu) != 0) && a < 1e-10f)) bad++;
    }
    __shared__ int cnt;
    if (t == 0) cnt = 0;
    __syncthreads();
    atomicAdd(&cnt, bad);
    __syncthreads();
    if (t == 0) flag[0] = (cnt > 800) ? 1 : 0;
}

// ---- stage layer params into fp32 ws buffers (dtype-agnostic downstream) ----
__global__ void k_stage(const void* __restrict__ W, long Woff,
                        const void* __restrict__ b, long boff,
                        const void* __restrict__ g1, const void* __restrict__ b1,
                        const void* __restrict__ g2, const void* __restrict__ b2, long L,
                        float* __restrict__ Wst, float* __restrict__ bst,
                        float* __restrict__ bn1s, float* __restrict__ bn2s,
                        const int* __restrict__ flag) {
    int f = flag[0];
    long i = (long)blockIdx.x * 256 + threadIdx.x;
    const long NW_ = (long)(2 * AF + NF) * 128;  // 21632
    if (i < NW_) {
        Wst[i] = ldf(W, Woff + i, f);
    } else if (i < NW_ + 128) {
        long c = i - NW_;
        bst[c] = ldf(b, boff + c, f);
        bn1s[c] = ldf(g1, L * 128 + c, f);
        bn1s[128 + c] = ldf(b1, L * 128 + c, f);
        if (c < 64) {
            bn2s[c] = ldf(g2, L * 64 + c, f);
            bn2s[64 + c] = ldf(b2, L * 64 + c, f);
        }
    }
}

// ---- atom_fea = embedding[atom_num], stored bf16 in ws ----
__global__ void k_embed(const int* __restrict__ atom_num, const void* __restrict__ emb,
                        u16* __restrict__ af, const int* __restrict__ flag) {
    int f = flag[0];
    int i = blockIdx.x * 256 + threadIdx.x;
    if (i < N_ATOM * AF) {
        int n = i >> 6, c = i & 63;
        af[i] = f2b(ldf(emb, (long)atom_num[n] * AF + c, f));
    }
}

// ---- round-0 k_an (MODE=1 fallback): An = af @ W[64:128], unpacked layout ----
__global__ __launch_bounds__(256) void k_an(const u16* __restrict__ af,
                       const float* __restrict__ Wst, u16* __restrict__ An) {
    int wv = threadIdx.x >> 6;
    int lane = threadIdx.x & 63;
    int n = blockIdx.x * 4 + wv;
    float afv = b2f(af[n * AF + lane]);
    float a0 = 0.f, a1 = 0.f;
    for (int k = 0; k < AF; ++k) {
        float a = __shfl(afv, k, 64);
        a0 = fmaf(a, Wst[(AF + k) * 128 + lane], a0);
        a1 = fmaf(a, Wst[(AF + k) * 128 + 64 + lane], a1);
    }
    An[(long)n * 128 + lane] = f2b(a0);
    An[(long)n * 128 + 64 + lane] = f2b(a1);
}

// ---- precompute: R = af@W[0:64]+b (fp32 or bf16), An2 = af@W[64:128] (packed bf16) ----
__global__ __launch_bounds__(256) void k_asn(const u16* __restrict__ af,
                       const float* __restrict__ Wst, const float* __restrict__ bst,
                       float* __restrict__ Rf, u16* __restrict__ Rh,
                       u16* __restrict__ An2, int rf) {
    int lane = threadIdx.x & 63;
    int n = blockIdx.x * 4 + (threadIdx.x >> 6);
    float afv = b2f(af[n * AF + lane]);
    float r0 = bst[lane], r1 = bst[64 + lane];
    float q0 = 0.f, q1 = 0.f;
    #pragma unroll 8
    for (int k = 0; k < AF; ++k) {
        float a = rdl(afv, k);
        r0 = fmaf(a, Wst[k * 128 + lane], r0);
        r1 = fmaf(a, Wst[k * 128 + 64 + lane], r1);
        q0 = fmaf(a, Wst[(AF + k) * 128 + lane], q0);
        q1 = fmaf(a, Wst[(AF + k) * 128 + 64 + lane], q1);
    }
    long p = (long)n * 64 + lane;
    if (rf) {
        *(float2*)(Rf + p * 2) = make_float2(r0, r1);
    } else {
        ((u32*)Rh)[p] = (u32)f2b(r0) | ((u32)f2b(r1) << 16);
    }
    ((u32*)An2)[p] = (u32)f2b(q0) | ((u32)f2b(q1) << 16);
}

// ---- g-tier stats pass: compute gated pre-BN g = R + E + An for all edges,
// STORE g (fp32 float2 or fp16 packed), accumulate bn1 stats. 4-edge unroll:
// 8 independent FMA chains + batched loads (int4 idx, 4 nv rows, 4 An dwords)
// for latency hiding; no per-thread weight arrays (LDS, ds_read_b64 imm offset)
// so VGPR stays low and occupancy high.
template<int GF>   // 1 = fp32 g, 0 = fp16 g
__global__ __launch_bounds__(256) void k_gstat(const void* __restrict__ nbr_fea,
                       const int* __restrict__ nbr_idx,
                       const u16* __restrict__ An,
                       const float* __restrict__ Wst,
                       const float* __restrict__ Rf,
                       void* __restrict__ G,
                       float* __restrict__ statsOut,
                       const int* __restrict__ flag) {
    int f = flag[0];
    int lane = threadIdx.x & 63;
    int wv = threadIdx.x >> 6;
    int gwave = blockIdx.x * 4 + wv;
    int NW = gridDim.x * 4;
    __shared__ float2 wlds[NF][64];   // W_edge rows 128..168, packed (c, c+64)
    __shared__ float red[256];
    for (int i = threadIdx.x; i < NF * 64; i += 256) {
        int k = i >> 6, c = i & 63;
        wlds[k][c] = make_float2(Wst[(128 + k) * 128 + c],
                                 Wst[(128 + k) * 128 + 64 + c]);
    }
    __syncthreads();

    const u32* An32 = (const u32*)An;
    float sum0 = 0.f, ssq0 = 0.f, sum1 = 0.f, ssq1 = 0.f;

    for (int n = gwave; n < N_ATOM; n += NW) {
        float2 rr = *(const float2*)(Rf + ((long)n * 64 + lane) * 2);
        for (int mb = 0; mb < M_NBR; mb += 4) {
            long ra = (long)n * M_NBR + mb;
            int4 jj = *(const int4*)(nbr_idx + ra);   // 48n+16mb bytes: 16B aligned
            float nv0, nv1, nv2, nv3;
            if (f) {
                const float* np = (const float*)nbr_fea + ra * NF;
                nv0 = (lane < NF) ? np[lane] : 0.f;
                nv1 = (lane < NF) ? np[NF + lane] : 0.f;
                nv2 = (lane < NF) ? np[2 * NF + lane] : 0.f;
                nv3 = (lane < NF) ? np[3 * NF + lane] : 0.f;
            } else {
                const u16* np = (const u16*)nbr_fea + ra * NF;
                nv0 = (lane < NF) ? b2f(np[lane]) : 0.f;
                nv1 = (lane < NF) ? b2f(np[NF + lane]) : 0.f;
                nv2 = (lane < NF) ? b2f(np[2 * NF + lane]) : 0.f;
                nv3 = (lane < NF) ? b2f(np[3 * NF + lane]) : 0.f;
            }
            u32 qa = An32[(long)jj.x * 64 + lane];
            u32 qb = An32[(long)jj.y * 64 + lane];
            u32 qc = An32[(long)jj.z * 64 + lane];
            u32 qd = An32[(long)jj.w * 64 + lane];
            float e00 = rr.x, e01 = rr.y, e10 = rr.x, e11 = rr.y;
            float e20 = rr.x, e21 = rr.y, e30 = rr.x, e31 = rr.y;
            #pragma unroll
            for (int k = 0; k < NF; ++k) {
                float2 w = wlds[k][lane];          // ds_read_b64 offset:k*512
                float va = rdl(nv0, k);
                float vb = rdl(nv1, k);
                float vc = rdl(nv2, k);
                float vd = rdl(nv3, k);
                e00 = fmaf(va, w.x, e00);  e01 = fmaf(va, w.y, e01);
                e10 = fmaf(vb, w.x, e10);  e11 = fmaf(vb, w.y, e11);
                e20 = fmaf(vc, w.x, e20);  e21 = fmaf(vc, w.y, e21);
                e30 = fmaf(vd, w.x, e30);  e31 = fmaf(vd, w.y, e31);
            }
            float g00 = e00 + b2f((u16)(qa & 0xffffu));
            float g01 = e01 + b2f((u16)(qa >> 16));
            float g10 = e10 + b2f((u16)(qb & 0xffffu));
            float g11 = e11 + b2f((u16)(qb >> 16));
            float g20 = e20 + b2f((u16)(qc & 0xffffu));
            float g21 = e21 + b2f((u16)(qc >> 16));
            float g30 = e30 + b2f((u16)(qd & 0xffffu));
            float g31 = e31 + b2f((u16)(qd >> 16));
            if (GF) {
                float2* Gf = (float2*)G;
                Gf[(ra + 0) * 64 + lane] = make_float2(g00, g01);
                Gf[(ra + 1) * 64 + lane] = make_float2(g10, g11);
                Gf[(ra + 2) * 64 + lane] = make_float2(g20, g21);
                Gf[(ra + 3) * 64 + lane] = make_float2(g30, g31);
            } else {
                u32* Gh = (u32*)G;
                Gh[(ra + 0) * 64 + lane] = (u32)__half_as_ushort(__float2half(g00))
                                         | ((u32)__half_as_ushort(__float2half(g01)) << 16);
                Gh[(ra + 1) * 64 + lane] = (u32)__half_as_ushort(__float2half(g10))
                                         | ((u32)__half_as_ushort(__float2half(g11)) << 16);
                Gh[(ra + 2) * 64 + lane] = (u32)__half_as_ushort(__float2half(g20))
                                         | ((u32)__half_as_ushort(__float2half(g21)) << 16);
                Gh[(ra + 3) * 64 + lane] = (u32)__half_as_ushort(__float2half(g30))
                                         | ((u32)__half_as_ushort(__float2half(g31)) << 16);
            }
            sum0 += g00 + g10 + g20 + g30;
            ssq0 += g00 * g00 + g10 * g10 + g20 * g20 + g30 * g30;
            sum1 += g01 + g11 + g21 + g31;
            ssq1 += g01 * g01 + g11 * g11 + g21 * g21 + g31 * g31;
        }
    }

    red[threadIdx.x] = 0.f;
    __syncthreads();
    atomicAdd(&red[lane], sum0);
    atomicAdd(&red[64 + lane], sum1);
    atomicAdd(&red[128 + lane], ssq0);
    atomicAdd(&red[192 + lane], ssq1);
    __syncthreads();
    atomicAdd(&statsOut[threadIdx.x], red[threadIdx.x]);
}

// ---- g-tier apply pass: stream g, apply bn1 affine + sigmoid*softplus,
// per-atom neighbor sum, bn2 stats. Pure memory-bound streaming.
template<int GF>
__global__ __launch_bounds__(256) void k_gapply(const void* __restrict__ G,
                       const float* __restrict__ st1,
                       u16* __restrict__ summed,
                       float* __restrict__ statsOut) {
    int lane = threadIdx.x & 63;
    int wv = threadIdx.x >> 6;
    int gwave = blockIdx.x * 4 + wv;
    int NW = gridDim.x * 4;
    float s0 = st1[lane],        s1 = st1[lane + 64];
    float t0 = st1[128 + lane],  t1 = st1[192 + lane];
    float sum0 = 0.f, ssq0 = 0.f;
    for (int n = gwave; n < N_ATOM; n += NW) {
        float asum = 0.f;
        long base = (long)n * M_NBR * 64 + lane;
        #pragma unroll
        for (int m = 0; m < M_NBR; ++m) {
            float g0, g1;
            if (GF) {
                float2 g = ((const float2*)G)[base + (long)m * 64];
                g0 = g.x; g1 = g.y;
            } else {
                u32 gp = ((const u32*)G)[base + (long)m * 64];
                g0 = __half2float(__ushort_as_half((u16)(gp & 0xffffu)));
                g1 = __half2float(__ushort_as_half((u16)(gp >> 16)));
            }
            asum += sigf(fmaf(g0, s0, t0)) * spf(fmaf(g1, s1, t1));
        }
        summed[(long)n * 64 + lane] = f2b(asum);
        sum0 += asum; ssq0 += asum * asum;
    }
    __shared__ float red[256];
    if (threadIdx.x < 128) red[threadIdx.x] = 0.f;
    __syncthreads();
    atomicAdd(&red[lane], sum0);
    atomicAdd(&red[64 + lane], ssq0);
    __syncthreads();
    if (threadIdx.x < 128) atomicAdd(&statsOut[threadIdx.x], red[threadIdx.x]);
}

// ---- legacy conv sweep (fallback tiers; unchanged from R4) ----
template<bool APPLY, int MODE>
__global__ __launch_bounds__(256) void k_conv(const void* __restrict__ nbr_fea,
                       const int* __restrict__ nbr_idx,
                       const u16* __restrict__ af, const u16* __restrict__ An,
                       const float* __restrict__ Wst, const float* __restrict__ bst,
                       const float* __restrict__ st1,
                       u16* __restrict__ summed,
                       float* __restrict__ statsOut,
                       const int* __restrict__ flag,
                       const float* __restrict__ Rf, const u16* __restrict__ Rh, int rf) {
    int f = flag[0];
    int lane = threadIdx.x & 63;
    int wv = threadIdx.x >> 6;
    int gwave = blockIdx.x * 4 + wv;
    int NW = gridDim.x * 4;
    __shared__ float2 wlds[NF][64];
    __shared__ float red[256];

    float s0 = 0.f, t0 = 0.f, s1 = 0.f, t1 = 0.f;
    if (APPLY) {
        s0 = st1[lane];        s1 = st1[lane + 64];
        t0 = st1[128 + lane];  t1 = st1[192 + lane];
    }
    float sum0 = 0.f, ssq0 = 0.f, sum1 = 0.f, ssq1 = 0.f;

    if (MODE == 0) {
        for (int i = threadIdx.x; i < NF * 64; i += 256) {
            int k = i >> 6, c = i & 63;
            wlds[k][c] = make_float2(Wst[(128 + k) * 128 + c],
                                     Wst[(128 + k) * 128 + 64 + c]);
        }
        __syncthreads();

        for (int n = gwave; n < N_ATOM; n += NW) {
            long p = (long)n * 64 + lane;
            float r0, r1;
            if (rf) {
                float2 rr = *(const float2*)(Rf + p * 2);
                r0 = rr.x; r1 = rr.y;
            } else {
                u32 rr = ((const u32*)Rh)[p];
                r0 = b2f((u16)(rr & 0xffffu)); r1 = b2f((u16)(rr >> 16));
            }
            float asum = 0.f;
            for (int m = 0; m < M_NBR; m += 2) {
                long ra = (long)n * M_NBR + m;
                int2 jj = *(const int2*)(nbr_idx + ra);
                float nv0, nv1;
                if (f) {
                    const float* np = (const float*)nbr_fea + ra * NF;
                    nv0 = (lane < NF) ? np[lane] : 0.f;
                    nv1 = (lane < NF) ? np[NF + lane] : 0.f;
                } else {
                    const u16* np = (const u16*)nbr_fea + ra * NF;
                    nv0 = (lane < NF) ? b2f(np[lane]) : 0.f;
                    nv1 = (lane < NF) ? b2f(np[NF + lane]) : 0.f;
                }
                u32 qa = ((const u32*)An)[(long)jj.x * 64 + lane];
                u32 qb = ((const u32*)An)[(long)jj.y * 64 + lane];
                float ea0 = r0, ea1 = r1, eb0 = r0, eb1 = r1;
                #pragma unroll
                for (int k = 0; k < NF; ++k) {
                    float2 w = wlds[k][lane];
                    float va = rdl(nv0, k);
                    float vb = rdl(nv1, k);
                    ea0 = fmaf(va, w.x, ea0);
                    ea1 = fmaf(va, w.y, ea1);
                    eb0 = fmaf(vb, w.x, eb0);
                    eb1 = fmaf(vb, w.y, eb1);
                }
                float ga0 = ea0 + b2f((u16)(qa & 0xffffu));
                float ga1 = ea1 + b2f((u16)(qa >> 16));
                float gb0 = eb0 + b2f((u16)(qb & 0xffffu));
                float gb1 = eb1 + b2f((u16)(qb >> 16));
                if (APPLY) {
                    asum += sigf(fmaf(ga0, s0, t0)) * spf(fmaf(ga1, s1, t1));
                    asum += sigf(fmaf(gb0, s0, t0)) * spf(fmaf(gb1, s1, t1));
                } else {
                    sum0 += ga0 + gb0; ssq0 += ga0 * ga0 + gb0 * gb0;
                    sum1 += ga1 + gb1; ssq1 += ga1 * ga1 + gb1 * gb1;
                }
            }
            if (APPLY) {
                summed[p] = f2b(asum);
                sum0 += asum; ssq0 += asum * asum;
            }
        }
    } else {
        float w0[NF], w1[NF];
        #pragma unroll
        for (int k = 0; k < NF; ++k) {
            w0[k] = Wst[(128 + k) * 128 + lane];
            w1[k] = Wst[(128 + k) * 128 + 64 + lane];
        }
        float b0 = bst[lane];
        float b1 = bst[64 + lane];
        for (int n = gwave; n < N_ATOM; n += NW) {
            float afv = b2f(af[n * AF + lane]);
            float as0 = b0, as1 = b1;
            for (int k = 0; k < AF; ++k) {
                float a = __shfl(afv, k, 64);
                as0 = fmaf(a, Wst[k * 128 + lane], as0);
                as1 = fmaf(a, Wst[k * 128 + 64 + lane], as1);
            }
            float asum = 0.f;
            for (int m = 0; m < M_NBR; ++m) {
                long r = (long)n * M_NBR + m;
                int j = nbr_idx[r];
                float nv = (lane < NF) ? ldf(nbr_fea, r * NF + lane, f) : 0.f;
                float e0 = as0, e1 = as1;
                #pragma unroll
                for (int k = 0; k < NF; ++k) {
                    float v = __shfl(nv, k, 64);
                    e0 = fmaf(v, w0[k], e0);
                    e1 = fmaf(v, w1[k], e1);
                }
                float g0, g1;
                if (MODE == 2) {
                    float aj = b2f(af[(long)j * AF + lane]);
                    float an0 = 0.f, an1 = 0.f;
                    for (int k = 0; k < AF; ++k) {
                        float a = __shfl(aj, k, 64);
                        an0 = fmaf(a, Wst[(AF + k) * 128 + lane], an0);
                        an1 = fmaf(a, Wst[(AF + k) * 128 + 64 + lane], an1);
                    }
                    g0 = e0 + an0; g1 = e1 + an1;
                } else {
                    g0 = e0 + b2f(An[(long)j * 128 + lane]);
                    g1 = e1 + b2f(An[(long)j * 128 + 64 + lane]);
                }
                if (APPLY) {
                    float ft = sigf(fmaf(g0, s0, t0));
                    float cc = spf(fmaf(g1, s1, t1));
                    asum += ft * cc;
                } else {
                    sum0 += g0; ssq0 += g0 * g0;
                    sum1 += g1; ssq1 += g1 * g1;
                }
            }
            if (APPLY) {
                summed[(long)n * 64 + lane] = f2b(asum);
                sum0 += asum; ssq0 += asum * asum;
            }
        }
    }

    if (APPLY) {
        if (threadIdx.x < 128) red[threadIdx.x] = 0.f;
        __syncthreads();
        atomicAdd(&red[lane], sum0);
        atomicAdd(&red[64 + lane], ssq0);
        __syncthreads();
        if (threadIdx.x < 128) atomicAdd(&statsOut[threadIdx.x], red[threadIdx.x]);
    } else {
        red[threadIdx.x] = 0.f;
        __syncthreads();
        atomicAdd(&red[lane], sum0);
        atomicAdd(&red[64 + lane], sum1);
        atomicAdd(&red[128 + lane], ssq0);
        atomicAdd(&red[192 + lane], ssq1);
        __syncthreads();
        atomicAdd(&statsOut[threadIdx.x], red[threadIdx.x]);
    }
}

__global__ void k_bn1(const float* __restrict__ stats, const float* __restrict__ bn1s,
                      float* __restrict__ st) {
    int c = threadIdx.x;  // 128
    float cnt = (float)N_ATOM * (float)M_NBR;
    float mu = stats[c] / cnt;
    float var = fmaxf(stats[128 + c] / cnt - mu * mu, 0.0f);
    float s = bn1s[c] * rsqrtf(var + EPS);
    st[c] = s;
    st[128 + c] = bn1s[128 + c] - mu * s;
}

__global__ void k_bn2(const float* __restrict__ stats, const float* __restrict__ bn2s,
                      float* __restrict__ st) {
    int c = threadIdx.x;  // 64
    float cnt = (float)N_ATOM;
    float mu = stats[c] / cnt;
    float var = fmaxf(stats[64 + c] / cnt - mu * mu, 0.0f);
    float s = bn2s[c] * rsqrtf(var + EPS);
    st[c] = s;
    st[64 + c] = bn2s[64 + c] - mu * s;
}

__global__ void k_update(u16* __restrict__ af, const u16* __restrict__ summed,
                         const float* __restrict__ st2) {
    int i = blockIdx.x * 256 + threadIdx.x;
    if (i < N_ATOM * 64) {
        int c = i & 63;
        float v = fmaf(b2f(summed[i]), st2[c], st2[64 + c]);
        af[i] = f2b(spf(b2f(af[i]) + v));
    }
}

__global__ void k_pool(const u16* __restrict__ af, const int* __restrict__ cidx,
                       float* __restrict__ crysp) {
    int b = blockIdx.x;
    int ch = threadIdx.x & 63;
    int part = threadIdx.x >> 6;
    float acc = 0.f;
    for (int k = part; k < APC; k += 4) {
        int a = cidx[b * APC + k];
        acc += b2f(af[(long)a * 64 + ch]);
    }
    __shared__ float red[256];
    red[threadIdx.x] = acc;
    __syncthreads();
    if (part == 0) {
        float s = red[ch] + red[64 + ch] + red[128 + ch] + red[192 + ch];
        crysp[b * 64 + ch] = spf(s * (1.0f / APC));
    }
}

__global__ void k_head(const float* __restrict__ crysp, const void* __restrict__ Wfc,
                       const void* __restrict__ bfc, const void* __restrict__ Wout,
                       const void* __restrict__ bout, void* __restrict__ outv,
                       const int* __restrict__ flag) {
    int f = flag[0];
    int b = blockIdx.x;
    int t = threadIdx.x;  // 128
    __shared__ float cr[64];
    __shared__ float h[HF];
    if (t < 64) cr[t] = crysp[b * 64 + t];
    __syncthreads();
    float acc = ldf(bfc, t, f);
    for (int k = 0; k < 64; ++k) acc = fmaf(cr[k], ldf(Wfc, (long)k * HF + t, f), acc);
    h[t] = spf(acc);
    __syncthreads();
    if (t < HID) {
        float o = ldf(bout, t, f);
        for (int k = 0; k < HF; ++k) o = fmaf(h[k], ldf(Wout, (long)k * HID + t, f), o);
        if (f) ((float*)outv)[b * HID + t] = o;
        else   ((u16*)outv)[b * HID + t] = f2b(o);
    }
}

extern "C" void kernel_launch(void* const* d_in, const int* in_sizes, int n_in,
                              void* d_out, int out_size, void* d_ws, size_t ws_size,
                              hipStream_t stream) {
    const int* atom_num = (const int*)d_in[0];
    const void* nbr_fea = d_in[1];
    const int* nbr_idx  = (const int*)d_in[2];
    const int* cidx     = (const int*)d_in[3];
    const void* emb     = d_in[4];
    const void* W_full  = d_in[5];
    const void* b_full  = d_in[6];
    const void* bn1_g   = d_in[7];
    const void* bn1_b   = d_in[8];
    const void* bn2_g   = d_in[9];
    const void* bn2_b   = d_in[10];
    const void* W_fc    = d_in[11];
    const void* b_fc    = d_in[12];
    const void* W_out   = d_in[13];
    const void* b_out   = d_in[14];

    // ---- ws layout: control + staging first, big arrays after ----
    char* wsb = (char*)d_ws;
    int*   flag   = (int*)wsb;                          // 16 B
    float* stats1 = (float*)(wsb + 16);                 // 256
    float* st1    = stats1 + 256;                       // 256
    float* stats2 = st1 + 256;                          // 128
    float* st2    = stats2 + 128;                       // 128
    float* crysp  = st2 + 128;                          // 6400
    float* Wst    = crysp + 6400;                       // 21632
    float* bst    = Wst + 21632;                        // 128
    float* bn1s   = bst + 128;                          // 256
    float* bn2s   = bn1s + 256;                         // 128
    u16*   af     = (u16*)(bn2s + 128);                 // N*64 bf16 = 12.8 MB
    u16*   summed = af + (long)N_ATOM * 64;             // N*64 bf16 = 12.8 MB
    u16*   An     = summed + (long)N_ATOM * 64;         // N*128 bf16 = 25.6 MB
    char*  afterAn = (char*)(An + (long)N_ATOM * 128);
    float* Rf = (float*)afterAn;                        // N*128 fp32 = 51.2 MB (rf=1)
    u16*   Rh = (u16*)afterAn;                          // N*128 bf16 = 25.6 MB (rf=0)
    char*  afterRf = afterAn + (size_t)N_ATOM * 128 * 4;
    void*  G = (void*)afterRf;                          // g buffer (fp32 614.4 MB / fp16 307.2 MB)

    size_t off_afterAn = (size_t)(afterAn - wsb);
    size_t need_f2  = off_afterAn + (size_t)N_ATOM * 128 * 4;
    size_t need_f2h = off_afterAn + (size_t)N_ATOM * 128 * 2;
    size_t need_f1  = off_afterAn;
    const size_t GBYTES32 = (size_t)N_ATOM * M_NBR * 128 * 4;  // 614.4 MB
    const size_t GBYTES16 = (size_t)N_ATOM * M_NBR * 128 * 2;  // 307.2 MB
    size_t need_TA = need_f2 + GBYTES32;
    size_t need_TB = need_f2 + GBYTES16;
    int gf = (ws_size >= need_TA) ? 1 : ((ws_size >= need_TB) ? 0 : -1);
    int rf = (ws_size >= need_f2) ? 1 : ((ws_size >= need_f2h) ? 0 : -1);
    bool f1 = ws_size >= need_f1;

    k_probe<<<1, 256, 0, stream>>>((const u16*)nbr_fea, flag);
    k_embed<<<(N_ATOM * 64 + 255) / 256, 256, 0, stream>>>(atom_num, emb, af, flag);

    const long WROWS = (long)(2 * AF + NF) * 128;  // 21632
    for (int L = 0; L < NC; ++L) {
        hipMemsetAsync(stats1, 0, 768 * sizeof(float), stream);
        k_stage<<<(int)((WROWS + 128 + 255) / 256), 256, 0, stream>>>(
            W_full, (long)L * WROWS, b_full, (long)L * 128,
            bn1_g, bn1_b, bn2_g, bn2_b, (long)L,
            Wst, bst, bn1s, bn2s, flag);
        if (gf >= 0) {
            // g-tier: compute+store gate once, stream it in apply
            k_asn<<<N_ATOM / 4, 256, 0, stream>>>(af, Wst, bst, Rf, Rh, An, 1);
            if (gf == 1)
                k_gstat<1><<<2500, 256, 0, stream>>>(nbr_fea, nbr_idx, An, Wst, Rf,
                                                     G, stats1, flag);
            else
                k_gstat<0><<<2500, 256, 0, stream>>>(nbr_fea, nbr_idx, An, Wst, Rf,
                                                     G, stats1, flag);
            k_bn1<<<1, 128, 0, stream>>>(stats1, bn1s, st1);
            if (gf == 1)
                k_gapply<1><<<2500, 256, 0, stream>>>(G, st1, summed, stats2);
            else
                k_gapply<0><<<2500, 256, 0, stream>>>(G, st1, summed, stats2);
        } else if (rf >= 0) {
            k_asn<<<N_ATOM / 4, 256, 0, stream>>>(af, Wst, bst, Rf, Rh, An, rf);
            k_conv<false, 0><<<2500, 256, 0, stream>>>(nbr_fea, nbr_idx, af, An,
                Wst, bst, nullptr, nullptr, stats1, flag, Rf, Rh, rf);
            k_bn1<<<1, 128, 0, stream>>>(stats1, bn1s, st1);
            k_conv<true, 0><<<2500, 256, 0, stream>>>(nbr_fea, nbr_idx, af, An,
                Wst, bst, st1, summed, stats2, flag, Rf, Rh, rf);
        } else if (f1) {
            k_an<<<N_ATOM / 4, 256, 0, stream>>>(af, Wst, An);
            k_conv<false, 1><<<2500, 256, 0, stream>>>(nbr_fea, nbr_idx, af, An,
                Wst, bst, nullptr, nullptr, stats1, flag, nullptr, nullptr, 0);
            k_bn1<<<1, 128, 0, stream>>>(stats1, bn1s, st1);
            k_conv<true, 1><<<2500, 256, 0, stream>>>(nbr_fea, nbr_idx, af, An,
                Wst, bst, st1, summed, stats2, flag, nullptr, nullptr, 0);
        } else {
            k_conv<false, 2><<<2500, 256, 0, stream>>>(nbr_fea, nbr_idx, af, nullptr,
                Wst, bst, nullptr, nullptr, stats1, flag, nullptr, nullptr, 0);
            k_bn1<<<1, 128, 0, stream>>>(stats1, bn1s, st1);
            k_conv<true, 2><<<2500, 256, 0, stream>>>(nbr_fea, nbr_idx, af, nullptr,
                Wst, bst, st1, summed, stats2, flag, nullptr, nullptr, 0);
        }
        k_bn2<<<1, 64, 0, stream>>>(stats2, bn2s, st2);
        k_update<<<(N_ATOM * 64 + 255) / 256, 256, 0, stream>>>(af, summed, st2);
    }
    k_pool<<<N0C, 256, 0, stream>>>(af, cidx, crysp);
    k_head<<<N0C, HF, 0, stream>>>(crysp, W_fc, b_fc, W_out, b_out, d_out, flag);
}

// Round 6
// 2724.287 us; speedup vs baseline: 2.4402x; 1.3559x over previous
//
#include <hip/hip_runtime.h>
#include <hip/hip_fp16.h>

#define N_ATOM 100000
#define M_NBR  12
#define NF     41
#define AF     64
#define NC     3
#define N0C    100
#define APC    1000
#define HF     128
#define HID    64
#define EPS    1e-5f
#define NTILE  75000   // 1.2M edges / 16 rows per MFMA tile

typedef unsigned short u16;
typedef unsigned int   u32;
typedef _Float16 half8 __attribute__((ext_vector_type(8)));
typedef float    f32x4 __attribute__((ext_vector_type(4)));

__device__ __forceinline__ float b2f(u16 u) {
    return __uint_as_float(((u32)u) << 16);
}
__device__ __forceinline__ u16 f2b(float f) {
    u32 x = __float_as_uint(f);
    u32 r = x + 0x7fffu + ((x >> 16) & 1u);
    return (u16)(r >> 16);
}
// dtype-flexible load: f==1 -> buffer is float32, else bf16
__device__ __forceinline__ float ldf(const void* p, long i, int f) {
    if (f) return ((const float*)p)[i];
    return b2f(((const u16*)p)[i]);
}
__device__ __forceinline__ float spf(float x) {           // softplus, stable
    return fmaxf(x, 0.0f) + log1pf(expf(-fabsf(x)));
}
__device__ __forceinline__ float sigf(float x) {
    return 1.0f / (1.0f + expf(-x));
}
// guaranteed v_readlane broadcast (uniform lane, SGPR result, no ds_bpermute)
__device__ __forceinline__ float rdl(float v, int l) {
    return __uint_as_float((u32)__builtin_amdgcn_readlane(__float_as_uint(v), l));
}
__device__ __forceinline__ u32 packh2(float a, float b) {
    return (u32)__half_as_ushort(__float2half(a))
         | ((u32)__half_as_ushort(__float2half(b)) << 16);
}

// ---- dtype probe: decode first 8192 u16 of nbr_fea as bf16; count implausible ----
__global__ void k_probe(const u16* __restrict__ nf, int* __restrict__ flag) {
    int t = threadIdx.x;  // 256
    int bad = 0;
    for (int i = t; i < 8192; i += 256) {
        u16 u = nf[i];
        float v = b2f(u);
        float a = fabsf(v);
        if (!(a <= 1024.0f) || (((u & 0x7fffu) != 0) && a < 1e-10f)) bad++;
    }
    __shared__ int cnt;
    if (t == 0) cnt = 0;
    __syncthreads();
    atomicAdd(&cnt, bad);
    __syncthreads();
    if (t == 0) flag[0] = (cnt > 800) ? 1 : 0;
}

// ---- stage layer params into fp32 ws buffers (dtype-agnostic downstream) ----
__global__ void k_stage(const void* __restrict__ W, long Woff,
                        const void* __restrict__ b, long boff,
                        const void* __restrict__ g1, const void* __restrict__ b1,
                        const void* __restrict__ g2, const void* __restrict__ b2, long L,
                        float* __restrict__ Wst, float* __restrict__ bst,
                        float* __restrict__ bn1s, float* __restrict__ bn2s,
                        const int* __restrict__ flag) {
    int f = flag[0];
    long i = (long)blockIdx.x * 256 + threadIdx.x;
    const long NW_ = (long)(2 * AF + NF) * 128;  // 21632
    if (i < NW_) {
        Wst[i] = ldf(W, Woff + i, f);
    } else if (i < NW_ + 128) {
        long c = i - NW_;
        bst[c] = ldf(b, boff + c, f);
        bn1s[c] = ldf(g1, L * 128 + c, f);
        bn1s[128 + c] = ldf(b1, L * 128 + c, f);
        if (c < 64) {
            bn2s[c] = ldf(g2, L * 64 + c, f);
            bn2s[64 + c] = ldf(b2, L * 64 + c, f);
        }
    }
}

// ---- atom_fea = embedding[atom_num], stored bf16 in ws ----
__global__ void k_embed(const int* __restrict__ atom_num, const void* __restrict__ emb,
                        u16* __restrict__ af, const int* __restrict__ flag) {
    int f = flag[0];
    int i = blockIdx.x * 256 + threadIdx.x;
    if (i < N_ATOM * AF) {
        int n = i >> 6, c = i & 63;
        af[i] = f2b(ldf(emb, (long)atom_num[n] * AF + c, f));
    }
}

// ---- one-time: nbr_fea -> fp16, swizzled into MFMA A-fragment layout ----
// Tile = 16 edges x K=64 (41 valid, zero pad). u16 index within tile:
//   ks*512 + grp*128 + row*8 + i   where k = ks*32 + grp*8 + i, row = edge&15.
// A wave's A-frag load (lane l): 16B at tile*2048B + ks*1024B + (l>>4)*256B + (l&15)*16B
// -> fully coalesced 1KB per instruction.
__global__ void k_nbrcvt(const void* __restrict__ nf, u32* __restrict__ Abuf,
                         const int* __restrict__ flag) {
    int f = flag[0];
    long d = (long)blockIdx.x * 256 + threadIdx.x;   // output dword index
    if (d >= (long)NTILE * 512) return;
    int tile = (int)(d >> 9);
    int rem  = (int)d & 511;
    int ks   = rem >> 8;
    int rem2 = rem & 255;
    int grp  = rem2 >> 6;
    int rem3 = rem2 & 63;
    int row  = rem3 >> 2;
    int kd   = rem3 & 3;
    int k0   = ks * 32 + grp * 8 + kd * 2;
    long e   = (long)tile * 16 + row;
    float v0 = (k0 < NF)     ? ldf(nf, e * NF + k0, f)     : 0.f;
    float v1 = (k0 + 1 < NF) ? ldf(nf, e * NF + k0 + 1, f) : 0.f;
    Abuf[d] = packh2(v0, v1);
}

// ---- round-0 k_an (MODE=1 fallback): An = af @ W[64:128], unpacked layout ----
__global__ __launch_bounds__(256) void k_an(const u16* __restrict__ af,
                       const float* __restrict__ Wst, u16* __restrict__ An) {
    int wv = threadIdx.x >> 6;
    int lane = threadIdx.x & 63;
    int n = blockIdx.x * 4 + wv;
    float afv = b2f(af[n * AF + lane]);
    float a0 = 0.f, a1 = 0.f;
    for (int k = 0; k < AF; ++k) {
        float a = __shfl(afv, k, 64);
        a0 = fmaf(a, Wst[(AF + k) * 128 + lane], a0);
        a1 = fmaf(a, Wst[(AF + k) * 128 + 64 + lane], a1);
    }
    An[(long)n * 128 + lane] = f2b(a0);
    An[(long)n * 128 + 64 + lane] = f2b(a1);
}

// ---- precompute: R = af@W[0:64]+b (fp32 or bf16), An2 = af@W[64:128] (packed bf16) ----
__global__ __launch_bounds__(256) void k_asn(const u16* __restrict__ af,
                       const float* __restrict__ Wst, const float* __restrict__ bst,
                       float* __restrict__ Rf, u16* __restrict__ Rh,
                       u16* __restrict__ An2, int rf) {
    int lane = threadIdx.x & 63;
    int n = blockIdx.x * 4 + (threadIdx.x >> 6);
    float afv = b2f(af[n * AF + lane]);
    float r0 = bst[lane], r1 = bst[64 + lane];
    float q0 = 0.f, q1 = 0.f;
    #pragma unroll 8
    for (int k = 0; k < AF; ++k) {
        float a = rdl(afv, k);
        r0 = fmaf(a, Wst[k * 128 + lane], r0);
        r1 = fmaf(a, Wst[k * 128 + 64 + lane], r1);
        q0 = fmaf(a, Wst[(AF + k) * 128 + lane], q0);
        q1 = fmaf(a, Wst[(AF + k) * 128 + 64 + lane], q1);
    }
    long p = (long)n * 64 + lane;
    if (rf) {
        *(float2*)(Rf + p * 2) = make_float2(r0, r1);
    } else {
        ((u32*)Rh)[p] = (u32)f2b(r0) | ((u32)f2b(r1) << 16);
    }
    ((u32*)An2)[p] = (u32)f2b(q0) | ((u32)f2b(q1) << 16);
}

// ---- MFMA g-pass: E = A(nbr,f16) @ B(W_edge,f16) via mfma_f32_16x16x32_f16;
// epilogue adds R[n] + An[j] in the verified D layout (col=lane&15,
// row=(lane>>4)*4+reg), accumulates bn1 stats, stores g packed fp16.
// B frags (2 ks x 8 nt, zero-padded K) staged in 16 KB LDS.
__global__ __launch_bounds__(256) void k_gmfma(
        const u16* __restrict__ Abuf, const int* __restrict__ nbr_idx,
        const u16* __restrict__ An, const float* __restrict__ Wst,
        const float* __restrict__ Rf, u32* __restrict__ G,
        float* __restrict__ statsOut) {
    int lane = threadIdx.x & 63;
    int wv = threadIdx.x >> 6;
    int gw = blockIdx.x * 4 + wv;
    int NW = gridDim.x * 4;
    __shared__ u16 Blds[8192];    // 16 KB: [ks][nt][grp][col][8]
    __shared__ float red[256];
    for (int i = threadIdx.x; i < 8192; i += 256) {
        int ks = i >> 12;
        int r1 = i & 4095;
        int nt = r1 >> 9;
        int r2 = r1 & 511;
        int grp = r2 >> 7;
        int r3 = r2 & 127;
        int col = r3 >> 3;
        int ii = r3 & 7;
        int k = ks * 32 + grp * 8 + ii;
        float v = (k < NF) ? Wst[(128 + k) * 128 + nt * 16 + col] : 0.f;
        Blds[i] = __half_as_ushort(__float2half(v));
    }
    red[threadIdx.x] = 0.f;
    __syncthreads();

    const u32* An32 = (const u32*)An;
    const float2* R2 = (const float2*)Rf;
    int sub = ((lane >> 4) << 7) + ((lane & 15) << 3);   // u16 offset in frag
    float sL[4] = {0,0,0,0}, qL[4] = {0,0,0,0};
    float sH[4] = {0,0,0,0}, qH[4] = {0,0,0,0};

    for (int t = gw; t < NTILE; t += NW) {
        f32x4 acc[8];
        #pragma unroll
        for (int i = 0; i < 8; ++i) acc[i] = (f32x4){0.f, 0.f, 0.f, 0.f};
        const u16* Ab = Abuf + (size_t)t * 1024;
        #pragma unroll
        for (int ks = 0; ks < 2; ++ks) {
            half8 a = *(const half8*)(Ab + ks * 512 + sub);
            #pragma unroll
            for (int nt = 0; nt < 8; ++nt) {
                half8 b = *(const half8*)(Blds + ks * 4096 + nt * 512 + sub);
                acc[nt] = __builtin_amdgcn_mfma_f32_16x16x32_f16(a, b, acc[nt], 0, 0, 0);
            }
        }
        #pragma unroll
        for (int r = 0; r < 4; ++r) {
            int e = (t << 4) + ((lane >> 4) << 2) + r;
            int n = e / 12;
            int j = nbr_idx[e];
            #pragma unroll
            for (int np = 0; np < 4; ++np) {
                int c = (np << 4) + (lane & 15);
                float2 rv = R2[(size_t)n * 64 + c];
                u32 q = An32[(size_t)j * 64 + c];
                float g0 = acc[np][r] + rv.x + b2f((u16)(q & 0xffffu));
                float g1 = acc[np + 4][r] + rv.y + b2f((u16)(q >> 16));
                G[(size_t)e * 64 + c] = packh2(g0, g1);
                sL[np] += g0;  qL[np] += g0 * g0;
                sH[np] += g1;  qH[np] += g1 * g1;
            }
        }
    }
    __syncthreads();
    #pragma unroll
    for (int np = 0; np < 4; ++np) {
        int c = (np << 4) + (lane & 15);
        atomicAdd(&red[c], sL[np]);
        atomicAdd(&red[64 + c], sH[np]);
        atomicAdd(&red[128 + c], qL[np]);
        atomicAdd(&red[192 + c], qH[np]);
    }
    __syncthreads();
    atomicAdd(&statsOut[threadIdx.x], red[threadIdx.x]);
}

// ---- g-tier stats pass (fallback, R5): compute+store g, bn1 stats ----
template<int GF>   // 1 = fp32 g, 0 = fp16 g
__global__ __launch_bounds__(256) void k_gstat(const void* __restrict__ nbr_fea,
                       const int* __restrict__ nbr_idx,
                       const u16* __restrict__ An,
                       const float* __restrict__ Wst,
                       const float* __restrict__ Rf,
                       void* __restrict__ G,
                       float* __restrict__ statsOut,
                       const int* __restrict__ flag) {
    int f = flag[0];
    int lane = threadIdx.x & 63;
    int wv = threadIdx.x >> 6;
    int gwave = blockIdx.x * 4 + wv;
    int NW = gridDim.x * 4;
    __shared__ float2 wlds[NF][64];
    __shared__ float red[256];
    for (int i = threadIdx.x; i < NF * 64; i += 256) {
        int k = i >> 6, c = i & 63;
        wlds[k][c] = make_float2(Wst[(128 + k) * 128 + c],
                                 Wst[(128 + k) * 128 + 64 + c]);
    }
    __syncthreads();

    const u32* An32 = (const u32*)An;
    float sum0 = 0.f, ssq0 = 0.f, sum1 = 0.f, ssq1 = 0.f;

    for (int n = gwave; n < N_ATOM; n += NW) {
        float2 rr = *(const float2*)(Rf + ((long)n * 64 + lane) * 2);
        for (int mb = 0; mb < M_NBR; mb += 2) {
            long ra = (long)n * M_NBR + mb;
            int2 jj = *(const int2*)(nbr_idx + ra);
            float nv0, nv1;
            if (f) {
                const float* np = (const float*)nbr_fea + ra * NF;
                nv0 = (lane < NF) ? np[lane] : 0.f;
                nv1 = (lane < NF) ? np[NF + lane] : 0.f;
            } else {
                const u16* np = (const u16*)nbr_fea + ra * NF;
                nv0 = (lane < NF) ? b2f(np[lane]) : 0.f;
                nv1 = (lane < NF) ? b2f(np[NF + lane]) : 0.f;
            }
            u32 qa = An32[(long)jj.x * 64 + lane];
            u32 qb = An32[(long)jj.y * 64 + lane];
            float e00 = rr.x, e01 = rr.y, e10 = rr.x, e11 = rr.y;
            #pragma unroll
            for (int k = 0; k < NF; ++k) {
                float2 w = wlds[k][lane];
                float va = rdl(nv0, k);
                float vb = rdl(nv1, k);
                e00 = fmaf(va, w.x, e00);  e01 = fmaf(va, w.y, e01);
                e10 = fmaf(vb, w.x, e10);  e11 = fmaf(vb, w.y, e11);
            }
            float g00 = e00 + b2f((u16)(qa & 0xffffu));
            float g01 = e01 + b2f((u16)(qa >> 16));
            float g10 = e10 + b2f((u16)(qb & 0xffffu));
            float g11 = e11 + b2f((u16)(qb >> 16));
            if (GF) {
                float2* Gf = (float2*)G;
                Gf[(ra + 0) * 64 + lane] = make_float2(g00, g01);
                Gf[(ra + 1) * 64 + lane] = make_float2(g10, g11);
            } else {
                u32* Gh = (u32*)G;
                Gh[(ra + 0) * 64 + lane] = packh2(g00, g01);
                Gh[(ra + 1) * 64 + lane] = packh2(g10, g11);
            }
            sum0 += g00 + g10; ssq0 += g00 * g00 + g10 * g10;
            sum1 += g01 + g11; ssq1 += g01 * g01 + g11 * g11;
        }
    }

    red[threadIdx.x] = 0.f;
    __syncthreads();
    atomicAdd(&red[lane], sum0);
    atomicAdd(&red[64 + lane], sum1);
    atomicAdd(&red[128 + lane], ssq0);
    atomicAdd(&red[192 + lane], ssq1);
    __syncthreads();
    atomicAdd(&statsOut[threadIdx.x], red[threadIdx.x]);
}

// ---- g-tier apply pass: stream g, bn1 affine + sigmoid*softplus, atom sum ----
template<int GF>
__global__ __launch_bounds__(256) void k_gapply(const void* __restrict__ G,
                       const float* __restrict__ st1,
                       u16* __restrict__ summed,
                       float* __restrict__ statsOut) {
    int lane = threadIdx.x & 63;
    int wv = threadIdx.x >> 6;
    int gwave = blockIdx.x * 4 + wv;
    int NW = gridDim.x * 4;
    float s0 = st1[lane],        s1 = st1[lane + 64];
    float t0 = st1[128 + lane],  t1 = st1[192 + lane];
    float sum0 = 0.f, ssq0 = 0.f;
    for (int n = gwave; n < N_ATOM; n += NW) {
        float asum = 0.f;
        long base = (long)n * M_NBR * 64 + lane;
        #pragma unroll
        for (int m = 0; m < M_NBR; ++m) {
            float g0, g1;
            if (GF) {
                float2 g = ((const float2*)G)[base + (long)m * 64];
                g0 = g.x; g1 = g.y;
            } else {
                u32 gp = ((const u32*)G)[base + (long)m * 64];
                g0 = __half2float(__ushort_as_half((u16)(gp & 0xffffu)));
                g1 = __half2float(__ushort_as_half((u16)(gp >> 16)));
            }
            asum += sigf(fmaf(g0, s0, t0)) * spf(fmaf(g1, s1, t1));
        }
        summed[(long)n * 64 + lane] = f2b(asum);
        sum0 += asum; ssq0 += asum * asum;
    }
    __shared__ float red[256];
    if (threadIdx.x < 128) red[threadIdx.x] = 0.f;
    __syncthreads();
    atomicAdd(&red[lane], sum0);
    atomicAdd(&red[64 + lane], ssq0);
    __syncthreads();
    if (threadIdx.x < 128) atomicAdd(&statsOut[threadIdx.x], red[threadIdx.x]);
}

// ---- legacy conv sweep (small-ws fallback tiers; unchanged) ----
template<bool APPLY, int MODE>
__global__ __launch_bounds__(256) void k_conv(const void* __restrict__ nbr_fea,
                       const int* __restrict__ nbr_idx,
                       const u16* __restrict__ af, const u16* __restrict__ An,
                       const float* __restrict__ Wst, const float* __restrict__ bst,
                       const float* __restrict__ st1,
                       u16* __restrict__ summed,
                       float* __restrict__ statsOut,
                       const int* __restrict__ flag,
                       const float* __restrict__ Rf, const u16* __restrict__ Rh, int rf) {
    int f = flag[0];
    int lane = threadIdx.x & 63;
    int wv = threadIdx.x >> 6;
    int gwave = blockIdx.x * 4 + wv;
    int NW = gridDim.x * 4;
    __shared__ float2 wlds[NF][64];
    __shared__ float red[256];

    float s0 = 0.f, t0 = 0.f, s1 = 0.f, t1 = 0.f;
    if (APPLY) {
        s0 = st1[lane];        s1 = st1[lane + 64];
        t0 = st1[128 + lane];  t1 = st1[192 + lane];
    }
    float sum0 = 0.f, ssq0 = 0.f, sum1 = 0.f, ssq1 = 0.f;

    if (MODE == 0) {
        for (int i = threadIdx.x; i < NF * 64; i += 256) {
            int k = i >> 6, c = i & 63;
            wlds[k][c] = make_float2(Wst[(128 + k) * 128 + c],
                                     Wst[(128 + k) * 128 + 64 + c]);
        }
        __syncthreads();

        for (int n = gwave; n < N_ATOM; n += NW) {
            long p = (long)n * 64 + lane;
            float r0, r1;
            if (rf) {
                float2 rr = *(const float2*)(Rf + p * 2);
                r0 = rr.x; r1 = rr.y;
            } else {
                u32 rr = ((const u32*)Rh)[p];
                r0 = b2f((u16)(rr & 0xffffu)); r1 = b2f((u16)(rr >> 16));
            }
            float asum = 0.f;
            for (int m = 0; m < M_NBR; m += 2) {
                long ra = (long)n * M_NBR + m;
                int2 jj = *(const int2*)(nbr_idx + ra);
                float nv0, nv1;
                if (f) {
                    const float* np = (const float*)nbr_fea + ra * NF;
                    nv0 = (lane < NF) ? np[lane] : 0.f;
                    nv1 = (lane < NF) ? np[NF + lane] : 0.f;
                } else {
                    const u16* np = (const u16*)nbr_fea + ra * NF;
                    nv0 = (lane < NF) ? b2f(np[lane]) : 0.f;
                    nv1 = (lane < NF) ? b2f(np[NF + lane]) : 0.f;
                }
                u32 qa = ((const u32*)An)[(long)jj.x * 64 + lane];
                u32 qb = ((const u32*)An)[(long)jj.y * 64 + lane];
                float ea0 = r0, ea1 = r1, eb0 = r0, eb1 = r1;
                #pragma unroll
                for (int k = 0; k < NF; ++k) {
                    float2 w = wlds[k][lane];
                    float va = rdl(nv0, k);
                    float vb = rdl(nv1, k);
                    ea0 = fmaf(va, w.x, ea0);
                    ea1 = fmaf(va, w.y, ea1);
                    eb0 = fmaf(vb, w.x, eb0);
                    eb1 = fmaf(vb, w.y, eb1);
                }
                float ga0 = ea0 + b2f((u16)(qa & 0xffffu));
                float ga1 = ea1 + b2f((u16)(qa >> 16));
                float gb0 = eb0 + b2f((u16)(qb & 0xffffu));
                float gb1 = eb1 + b2f((u16)(qb >> 16));
                if (APPLY) {
                    asum += sigf(fmaf(ga0, s0, t0)) * spf(fmaf(ga1, s1, t1));
                    asum += sigf(fmaf(gb0, s0, t0)) * spf(fmaf(gb1, s1, t1));
                } else {
                    sum0 += ga0 + gb0; ssq0 += ga0 * ga0 + gb0 * gb0;
                    sum1 += ga1 + gb1; ssq1 += ga1 * ga1 + gb1 * gb1;
                }
            }
            if (APPLY) {
                summed[p] = f2b(asum);
                sum0 += asum; ssq0 += asum * asum;
            }
        }
    } else {
        float w0[NF], w1[NF];
        #pragma unroll
        for (int k = 0; k < NF; ++k) {
            w0[k] = Wst[(128 + k) * 128 + lane];
            w1[k] = Wst[(128 + k) * 128 + 64 + lane];
        }
        float b0 = bst[lane];
        float b1 = bst[64 + lane];
        for (int n = gwave; n < N_ATOM; n += NW) {
            float afv = b2f(af[n * AF + lane]);
            float as0 = b0, as1 = b1;
            for (int k = 0; k < AF; ++k) {
                float a = __shfl(afv, k, 64);
                as0 = fmaf(a, Wst[k * 128 + lane], as0);
                as1 = fmaf(a, Wst[k * 128 + 64 + lane], as1);
            }
            float asum = 0.f;
            for (int m = 0; m < M_NBR; ++m) {
                long r = (long)n * M_NBR + m;
                int j = nbr_idx[r];
                float nv = (lane < NF) ? ldf(nbr_fea, r * NF + lane, f) : 0.f;
                float e0 = as0, e1 = as1;
                #pragma unroll
                for (int k = 0; k < NF; ++k) {
                    float v = __shfl(nv, k, 64);
                    e0 = fmaf(v, w0[k], e0);
                    e1 = fmaf(v, w1[k], e1);
                }
                float g0, g1;
                if (MODE == 2) {
                    float aj = b2f(af[(long)j * AF + lane]);
                    float an0 = 0.f, an1 = 0.f;
                    for (int k = 0; k < AF; ++k) {
                        float a = __shfl(aj, k, 64);
                        an0 = fmaf(a, Wst[(AF + k) * 128 + lane], an0);
                        an1 = fmaf(a, Wst[(AF + k) * 128 + 64 + lane], an1);
                    }
                    g0 = e0 + an0; g1 = e1 + an1;
                } else {
                    g0 = e0 + b2f(An[(long)j * 128 + lane]);
                    g1 = e1 + b2f(An[(long)j * 128 + 64 + lane]);
                }
                if (APPLY) {
                    float ft = sigf(fmaf(g0, s0, t0));
                    float cc = spf(fmaf(g1, s1, t1));
                    asum += ft * cc;
                } else {
                    sum0 += g0; ssq0 += g0 * g0;
                    sum1 += g1; ssq1 += g1 * g1;
                }
            }
            if (APPLY) {
                summed[(long)n * 64 + lane] = f2b(asum);
                sum0 += asum; ssq0 += asum * asum;
            }
        }
    }

    if (APPLY) {
        if (threadIdx.x < 128) red[threadIdx.x] = 0.f;
        __syncthreads();
        atomicAdd(&red[lane], sum0);
        atomicAdd(&red[64 + lane], ssq0);
        __syncthreads();
        if (threadIdx.x < 128) atomicAdd(&statsOut[threadIdx.x], red[threadIdx.x]);
    } else {
        red[threadIdx.x] = 0.f;
        __syncthreads();
        atomicAdd(&red[lane], sum0);
        atomicAdd(&red[64 + lane], sum1);
        atomicAdd(&red[128 + lane], ssq0);
        atomicAdd(&red[192 + lane], ssq1);
        __syncthreads();
        atomicAdd(&statsOut[threadIdx.x], red[threadIdx.x]);
    }
}

__global__ void k_bn1(const float* __restrict__ stats, const float* __restrict__ bn1s,
                      float* __restrict__ st) {
    int c = threadIdx.x;  // 128
    float cnt = (float)N_ATOM * (float)M_NBR;
    float mu = stats[c] / cnt;
    float var = fmaxf(stats[128 + c] / cnt - mu * mu, 0.0f);
    float s = bn1s[c] * rsqrtf(var + EPS);
    st[c] = s;
    st[128 + c] = bn1s[128 + c] - mu * s;
}

__global__ void k_bn2(const float* __restrict__ stats, const float* __restrict__ bn2s,
                      float* __restrict__ st) {
    int c = threadIdx.x;  // 64
    float cnt = (float)N_ATOM;
    float mu = stats[c] / cnt;
    float var = fmaxf(stats[64 + c] / cnt - mu * mu, 0.0f);
    float s = bn2s[c] * rsqrtf(var + EPS);
    st[c] = s;
    st[64 + c] = bn2s[64 + c] - mu * s;
}

__global__ void k_update(u16* __restrict__ af, const u16* __restrict__ summed,
                         const float* __restrict__ st2) {
    int i = blockIdx.x * 256 + threadIdx.x;
    if (i < N_ATOM * 64) {
        int c = i & 63;
        float v = fmaf(b2f(summed[i]), st2[c], st2[64 + c]);
        af[i] = f2b(spf(b2f(af[i]) + v));
    }
}

__global__ void k_pool(const u16* __restrict__ af, const int* __restrict__ cidx,
                       float* __restrict__ crysp) {
    int b = blockIdx.x;
    int ch = threadIdx.x & 63;
    int part = threadIdx.x >> 6;
    float acc = 0.f;
    for (int k = part; k < APC; k += 4) {
        int a = cidx[b * APC + k];
        acc += b2f(af[(long)a * 64 + ch]);
    }
    __shared__ float red[256];
    red[threadIdx.x] = acc;
    __syncthreads();
    if (part == 0) {
        float s = red[ch] + red[64 + ch] + red[128 + ch] + red[192 + ch];
        crysp[b * 64 + ch] = spf(s * (1.0f / APC));
    }
}

__global__ void k_head(const float* __restrict__ crysp, const void* __restrict__ Wfc,
                       const void* __restrict__ bfc, const void* __restrict__ Wout,
                       const void* __restrict__ bout, void* __restrict__ outv,
                       const int* __restrict__ flag) {
    int f = flag[0];
    int b = blockIdx.x;
    int t = threadIdx.x;  // 128
    __shared__ float cr[64];
    __shared__ float h[HF];
    if (t < 64) cr[t] = crysp[b * 64 + t];
    __syncthreads();
    float acc = ldf(bfc, t, f);
    for (int k = 0; k < 64; ++k) acc = fmaf(cr[k], ldf(Wfc, (long)k * HF + t, f), acc);
    h[t] = spf(acc);
    __syncthreads();
    if (t < HID) {
        float o = ldf(bout, t, f);
        for (int k = 0; k < HF; ++k) o = fmaf(h[k], ldf(Wout, (long)k * HID + t, f), o);
        if (f) ((float*)outv)[b * HID + t] = o;
        else   ((u16*)outv)[b * HID + t] = f2b(o);
    }
}

extern "C" void kernel_launch(void* const* d_in, const int* in_sizes, int n_in,
                              void* d_out, int out_size, void* d_ws, size_t ws_size,
                              hipStream_t stream) {
    const int* atom_num = (const int*)d_in[0];
    const void* nbr_fea = d_in[1];
    const int* nbr_idx  = (const int*)d_in[2];
    const int* cidx     = (const int*)d_in[3];
    const void* emb     = d_in[4];
    const void* W_full  = d_in[5];
    const void* b_full  = d_in[6];
    const void* bn1_g   = d_in[7];
    const void* bn1_b   = d_in[8];
    const void* bn2_g   = d_in[9];
    const void* bn2_b   = d_in[10];
    const void* W_fc    = d_in[11];
    const void* b_fc    = d_in[12];
    const void* W_out   = d_in[13];
    const void* b_out   = d_in[14];

    // ---- ws layout: control + staging first, big arrays after ----
    char* wsb = (char*)d_ws;
    int*   flag   = (int*)wsb;                          // 16 B
    float* stats1 = (float*)(wsb + 16);                 // 256
    float* st1    = stats1 + 256;                       // 256
    float* stats2 = st1 + 256;                          // 128
    float* st2    = stats2 + 128;                       // 128
    float* crysp  = st2 + 128;                          // 6400
    float* Wst    = crysp + 6400;                       // 21632
    float* bst    = Wst + 21632;                        // 128
    float* bn1s   = bst + 128;                          // 256
    float* bn2s   = bn1s + 256;                         // 128
    u16*   af     = (u16*)(bn2s + 128);                 // N*64 bf16 = 12.8 MB
    u16*   summed = af + (long)N_ATOM * 64;             // N*64 bf16 = 12.8 MB
    u16*   An     = summed + (long)N_ATOM * 64;         // N*128 bf16 = 25.6 MB
    char*  afterAn = (char*)(An + (long)N_ATOM * 128);
    float* Rf = (float*)afterAn;                        // N*128 fp32 = 51.2 MB
    u16*   Rh = (u16*)afterAn;
    char*  afterRf = afterAn + (size_t)N_ATOM * 128 * 4;
    void*  G = (void*)afterRf;                          // g buffer

    size_t off_afterAn = (size_t)(afterAn - wsb);
    size_t need_f2  = off_afterAn + (size_t)N_ATOM * 128 * 4;
    size_t need_f2h = off_afterAn + (size_t)N_ATOM * 128 * 2;
    size_t need_f1  = off_afterAn;
    const size_t GBYTES32 = (size_t)N_ATOM * M_NBR * 128 * 4;  // 614.4 MB
    const size_t GBYTES16 = (size_t)N_ATOM * M_NBR * 128 * 2;  // 307.2 MB
    const size_t ABYTES   = (size_t)NTILE * 2048;              // 153.6 MB
    u32* Abuf = (u32*)(afterRf + GBYTES16);             // MFMA tier only
    size_t need_M  = need_f2 + GBYTES16 + ABYTES;       // ~589 MB
    size_t need_TA = need_f2 + GBYTES32;
    size_t need_TB = need_f2 + GBYTES16;
    int mf = (ws_size >= need_M) ? 1 : 0;
    int gf = (ws_size >= need_TA) ? 1 : ((ws_size >= need_TB) ? 0 : -1);
    int rf = (ws_size >= need_f2) ? 1 : ((ws_size >= need_f2h) ? 0 : -1);
    bool f1 = ws_size >= need_f1;

    k_probe<<<1, 256, 0, stream>>>((const u16*)nbr_fea, flag);
    if (mf) {
        k_nbrcvt<<<(int)(((long)NTILE * 512 + 255) / 256), 256, 0, stream>>>(
            nbr_fea, Abuf, flag);
    }
    k_embed<<<(N_ATOM * 64 + 255) / 256, 256, 0, stream>>>(atom_num, emb, af, flag);

    const long WROWS = (long)(2 * AF + NF) * 128;  // 21632
    for (int L = 0; L < NC; ++L) {
        hipMemsetAsync(stats1, 0, 768 * sizeof(float), stream);
        k_stage<<<(int)((WROWS + 128 + 255) / 256), 256, 0, stream>>>(
            W_full, (long)L * WROWS, b_full, (long)L * 128,
            bn1_g, bn1_b, bn2_g, bn2_b, (long)L,
            Wst, bst, bn1s, bn2s, flag);
        if (mf) {
            // MFMA tier: edge GEMM on matrix cores, g stored fp16
            k_asn<<<N_ATOM / 4, 256, 0, stream>>>(af, Wst, bst, Rf, Rh, An, 1);
            k_gmfma<<<2500, 256, 0, stream>>>((const u16*)Abuf, nbr_idx, An, Wst,
                                              Rf, (u32*)G, stats1);
            k_bn1<<<1, 128, 0, stream>>>(stats1, bn1s, st1);
            k_gapply<0><<<2500, 256, 0, stream>>>(G, st1, summed, stats2);
        } else if (gf >= 0) {
            k_asn<<<N_ATOM / 4, 256, 0, stream>>>(af, Wst, bst, Rf, Rh, An, 1);
            if (gf == 1)
                k_gstat<1><<<2500, 256, 0, stream>>>(nbr_fea, nbr_idx, An, Wst, Rf,
                                                     G, stats1, flag);
            else
                k_gstat<0><<<2500, 256, 0, stream>>>(nbr_fea, nbr_idx, An, Wst, Rf,
                                                     G, stats1, flag);
            k_bn1<<<1, 128, 0, stream>>>(stats1, bn1s, st1);
            if (gf == 1)
                k_gapply<1><<<2500, 256, 0, stream>>>(G, st1, summed, stats2);
            else
                k_gapply<0><<<2500, 256, 0, stream>>>(G, st1, summed, stats2);
        } else if (rf >= 0) {
            k_asn<<<N_ATOM / 4, 256, 0, stream>>>(af, Wst, bst, Rf, Rh, An, rf);
            k_conv<false, 0><<<2500, 256, 0, stream>>>(nbr_fea, nbr_idx, af, An,
                Wst, bst, nullptr, nullptr, stats1, flag, Rf, Rh, rf);
            k_bn1<<<1, 128, 0, stream>>>(stats1, bn1s, st1);
            k_conv<true, 0><<<2500, 256, 0, stream>>>(nbr_fea, nbr_idx, af, An,
                Wst, bst, st1, summed, stats2, flag, Rf, Rh, rf);
        } else if (f1) {
            k_an<<<N_ATOM / 4, 256, 0, stream>>>(af, Wst, An);
            k_conv<false, 1><<<2500, 256, 0, stream>>>(nbr_fea, nbr_idx, af, An,
                Wst, bst, nullptr, nullptr, stats1, flag, nullptr, nullptr, 0);
            k_bn1<<<1, 128, 0, stream>>>(stats1, bn1s, st1);
            k_conv<true, 1><<<2500, 256, 0, stream>>>(nbr_fea, nbr_idx, af, An,
                Wst, bst, st1, summed, stats2, flag, nullptr, nullptr, 0);
        } else {
            k_conv<false, 2><<<2500, 256, 0, stream>>>(nbr_fea, nbr_idx, af, nullptr,
                Wst, bst, nullptr, nullptr, stats1, flag, nullptr, nullptr, 0);
            k_bn1<<<1, 128, 0, stream>>>(stats1, bn1s, st1);
            k_conv<true, 2><<<2500, 256, 0, stream>>>(nbr_fea, nbr_idx, af, nullptr,
                Wst, bst, st1, summed, stats2, flag, nullptr, nullptr, 0);
        }
        k_bn2<<<1, 64, 0, stream>>>(stats2, bn2s, st2);
        k_update<<<(N_ATOM * 64 + 255) / 256, 256, 0, stream>>>(af, summed, st2);
    }
    k_pool<<<N0C, 256, 0, stream>>>(af, cidx, crysp);
    k_head<<<N0C, HF, 0, stream>>>(crysp, W_fc, b_fc, W_out, b_out, d_out, flag);
}

// Round 8
// 2164.260 us; speedup vs baseline: 3.0716x; 1.2588x over previous
//
#include <hip/hip_runtime.h>
#include <hip/hip_fp16.h>

#define N_ATOM 100000
#define M_NBR  12
#define NF     41
#define AF     64
#define NC     3
#define N0C    100
#define APC    1000
#define HF     128
#define HID    64
#define EPS    1e-5f
#define NTILE  75000   // 1.2M edges / 16 rows per MFMA tile

typedef unsigned short u16;
typedef unsigned int   u32;
typedef _Float16 half8 __attribute__((ext_vector_type(8)));
typedef float    f32x4 __attribute__((ext_vector_type(4)));

__device__ __forceinline__ float b2f(u16 u) {
    return __uint_as_float(((u32)u) << 16);
}
__device__ __forceinline__ u16 f2b(float f) {
    u32 x = __float_as_uint(f);
    u32 r = x + 0x7fffu + ((x >> 16) & 1u);
    return (u16)(r >> 16);
}
// dtype-flexible load: f==1 -> buffer is float32, else bf16
__device__ __forceinline__ float ldf(const void* p, long i, int f) {
    if (f) return ((const float*)p)[i];
    return b2f(((const u16*)p)[i]);
}
// ---- native-rate transcendentals (R7): libm expf/log1pf + IEEE divide cost
// ~75 instr/pair and made k_gapply VALU-bound (81% busy @ 507 GB/s, R6 PMC).
// __expf/__logf lower to v_exp_f32/v_log_f32 (fast path, ~1-2 ulp);
// __builtin_amdgcn_rcpf is v_rcp_f32. Invisible vs the bf16 pipeline noise.
__device__ __forceinline__ float spf(float x) {    // softplus, stable, native
    return fmaxf(x, 0.0f) + __logf(1.0f + __expf(-fabsf(x)));
}
__device__ __forceinline__ float sigf(float x) {   // sigmoid, native
    return __builtin_amdgcn_rcpf(1.0f + __expf(-x));
}
// guaranteed v_readlane broadcast (uniform lane, SGPR result, no ds_bpermute)
__device__ __forceinline__ float rdl(float v, int l) {
    return __uint_as_float((u32)__builtin_amdgcn_readlane(__float_as_uint(v), l));
}
__device__ __forceinline__ u32 packh2(float a, float b) {
    return (u32)__half_as_ushort(__float2half(a))
         | ((u32)__half_as_ushort(__float2half(b)) << 16);
}

// ---- dtype probe: decode first 8192 u16 of nbr_fea as bf16; count implausible ----
__global__ void k_probe(const u16* __restrict__ nf, int* __restrict__ flag) {
    int t = threadIdx.x;  // 256
    int bad = 0;
    for (int i = t; i < 8192; i += 256) {
        u16 u = nf[i];
        float v = b2f(u);
        float a = fabsf(v);
        if (!(a <= 1024.0f) || (((u & 0x7fffu) != 0) && a < 1e-10f)) bad++;
    }
    __shared__ int cnt;
    if (t == 0) cnt = 0;
    __syncthreads();
    atomicAdd(&cnt, bad);
    __syncthreads();
    if (t == 0) flag[0] = (cnt > 800) ? 1 : 0;
}

// ---- stage layer params into fp32 ws buffers (dtype-agnostic downstream) ----
__global__ void k_stage(const void* __restrict__ W, long Woff,
                        const void* __restrict__ b, long boff,
                        const void* __restrict__ g1, const void* __restrict__ b1,
                        const void* __restrict__ g2, const void* __restrict__ b2, long L,
                        float* __restrict__ Wst, float* __restrict__ bst,
                        float* __restrict__ bn1s, float* __restrict__ bn2s,
                        const int* __restrict__ flag) {
    int f = flag[0];
    long i = (long)blockIdx.x * 256 + threadIdx.x;
    const long NW_ = (long)(2 * AF + NF) * 128;  // 21632
    if (i < NW_) {
        Wst[i] = ldf(W, Woff + i, f);
    } else if (i < NW_ + 128) {
        long c = i - NW_;
        bst[c] = ldf(b, boff + c, f);
        bn1s[c] = ldf(g1, L * 128 + c, f);
        bn1s[128 + c] = ldf(b1, L * 128 + c, f);
        if (c < 64) {
            bn2s[c] = ldf(g2, L * 64 + c, f);
            bn2s[64 + c] = ldf(b2, L * 64 + c, f);
        }
    }
}

// ---- atom_fea = embedding[atom_num], stored bf16 in ws ----
__global__ void k_embed(const int* __restrict__ atom_num, const void* __restrict__ emb,
                        u16* __restrict__ af, const int* __restrict__ flag) {
    int f = flag[0];
    int i = blockIdx.x * 256 + threadIdx.x;
    if (i < N_ATOM * AF) {
        int n = i >> 6, c = i & 63;
        af[i] = f2b(ldf(emb, (long)atom_num[n] * AF + c, f));
    }
}

// ---- one-time: nbr_fea -> fp16, swizzled into MFMA A-fragment layout ----
// Tile = 16 edges x K=64 (41 valid, zero pad). u16 index within tile:
//   ks*512 + grp*128 + row*8 + i   where k = ks*32 + grp*8 + i, row = edge&15.
__global__ void k_nbrcvt(const void* __restrict__ nf, u32* __restrict__ Abuf,
                         const int* __restrict__ flag) {
    int f = flag[0];
    long d = (long)blockIdx.x * 256 + threadIdx.x;   // output dword index
    if (d >= (long)NTILE * 512) return;
    int tile = (int)(d >> 9);
    int rem  = (int)d & 511;
    int ks   = rem >> 8;
    int rem2 = rem & 255;
    int grp  = rem2 >> 6;
    int rem3 = rem2 & 63;
    int row  = rem3 >> 2;
    int kd   = rem3 & 3;
    int k0   = ks * 32 + grp * 8 + kd * 2;
    long e   = (long)tile * 16 + row;
    float v0 = (k0 < NF)     ? ldf(nf, e * NF + k0, f)     : 0.f;
    float v1 = (k0 + 1 < NF) ? ldf(nf, e * NF + k0 + 1, f) : 0.f;
    Abuf[d] = packh2(v0, v1);
}

// ---- round-0 k_an (MODE=1 fallback): An = af @ W[64:128], unpacked layout ----
__global__ __launch_bounds__(256) void k_an(const u16* __restrict__ af,
                       const float* __restrict__ Wst, u16* __restrict__ An) {
    int wv = threadIdx.x >> 6;
    int lane = threadIdx.x & 63;
    int n = blockIdx.x * 4 + wv;
    float afv = b2f(af[n * AF + lane]);
    float a0 = 0.f, a1 = 0.f;
    for (int k = 0; k < AF; ++k) {
        float a = __shfl(afv, k, 64);
        a0 = fmaf(a, Wst[(AF + k) * 128 + lane], a0);
        a1 = fmaf(a, Wst[(AF + k) * 128 + 64 + lane], a1);
    }
    An[(long)n * 128 + lane] = f2b(a0);
    An[(long)n * 128 + 64 + lane] = f2b(a1);
}

// ---- precompute: R = af@W[0:64]+b (fp32 or bf16), An2 = af@W[64:128] (packed bf16) ----
__global__ __launch_bounds__(256) void k_asn(const u16* __restrict__ af,
                       const float* __restrict__ Wst, const float* __restrict__ bst,
                       float* __restrict__ Rf, u16* __restrict__ Rh,
                       u16* __restrict__ An2, int rf) {
    int lane = threadIdx.x & 63;
    int n = blockIdx.x * 4 + (threadIdx.x >> 6);
    float afv = b2f(af[n * AF + lane]);
    float r0 = bst[lane], r1 = bst[64 + lane];
    float q0 = 0.f, q1 = 0.f;
    #pragma unroll 8
    for (int k = 0; k < AF; ++k) {
        float a = rdl(afv, k);
        r0 = fmaf(a, Wst[k * 128 + lane], r0);
        r1 = fmaf(a, Wst[k * 128 + 64 + lane], r1);
        q0 = fmaf(a, Wst[(AF + k) * 128 + lane], q0);
        q1 = fmaf(a, Wst[(AF + k) * 128 + 64 + lane], q1);
    }
    long p = (long)n * 64 + lane;
    if (rf) {
        *(float2*)(Rf + p * 2) = make_float2(r0, r1);
    } else {
        ((u32*)Rh)[p] = (u32)f2b(r0) | ((u32)f2b(r1) << 16);
    }
    ((u32*)An2)[p] = (u32)f2b(q0) | ((u32)f2b(q1) << 16);
}

// ---- MFMA g-pass: E = A(nbr,f16) @ B(W_edge,f16) via mfma_f32_16x16x32_f16;
// epilogue adds R[n] + An[j] in the verified D layout (col=lane&15,
// row=(lane>>4)*4+reg), accumulates bn1 stats, stores g packed fp16.
__global__ __launch_bounds__(256) void k_gmfma(
        const u16* __restrict__ Abuf, const int* __restrict__ nbr_idx,
        const u16* __restrict__ An, const float* __restrict__ Wst,
        const float* __restrict__ Rf, u32* __restrict__ G,
        float* __restrict__ statsOut) {
    int lane = threadIdx.x & 63;
    int wv = threadIdx.x >> 6;
    int gw = blockIdx.x * 4 + wv;
    int NW = gridDim.x * 4;
    __shared__ u16 Blds[8192];    // 16 KB: [ks][nt][grp][col][8]
    __shared__ float red[256];
    for (int i = threadIdx.x; i < 8192; i += 256) {
        int ks = i >> 12;
        int r1 = i & 4095;
        int nt = r1 >> 9;
        int r2 = r1 & 511;
        int grp = r2 >> 7;
        int r3 = r2 & 127;
        int col = r3 >> 3;
        int ii = r3 & 7;
        int k = ks * 32 + grp * 8 + ii;
        float v = (k < NF) ? Wst[(128 + k) * 128 + nt * 16 + col] : 0.f;
        Blds[i] = __half_as_ushort(__float2half(v));
    }
    red[threadIdx.x] = 0.f;
    __syncthreads();

    const u32* An32 = (const u32*)An;
    const float2* R2 = (const float2*)Rf;
    int sub = ((lane >> 4) << 7) + ((lane & 15) << 3);   // u16 offset in frag
    float sL[4] = {0,0,0,0}, qL[4] = {0,0,0,0};
    float sH[4] = {0,0,0,0}, qH[4] = {0,0,0,0};

    for (int t = gw; t < NTILE; t += NW) {
        f32x4 acc[8];
        #pragma unroll
        for (int i = 0; i < 8; ++i) acc[i] = (f32x4){0.f, 0.f, 0.f, 0.f};
        const u16* Ab = Abuf + (size_t)t * 1024;
        #pragma unroll
        for (int ks = 0; ks < 2; ++ks) {
            half8 a = *(const half8*)(Ab + ks * 512 + sub);
            #pragma unroll
            for (int nt = 0; nt < 8; ++nt) {
                half8 b = *(const half8*)(Blds + ks * 4096 + nt * 512 + sub);
                acc[nt] = __builtin_amdgcn_mfma_f32_16x16x32_f16(a, b, acc[nt], 0, 0, 0);
            }
        }
        #pragma unroll
        for (int r = 0; r < 4; ++r) {
            int e = (t << 4) + ((lane >> 4) << 2) + r;
            int n = e / 12;
            int j = nbr_idx[e];
            #pragma unroll
            for (int np = 0; np < 4; ++np) {
                int c = (np << 4) + (lane & 15);
                float2 rv = R2[(size_t)n * 64 + c];
                u32 q = An32[(size_t)j * 64 + c];
                float g0 = acc[np][r] + rv.x + b2f((u16)(q & 0xffffu));
                float g1 = acc[np + 4][r] + rv.y + b2f((u16)(q >> 16));
                G[(size_t)e * 64 + c] = packh2(g0, g1);
                sL[np] += g0;  qL[np] += g0 * g0;
                sH[np] += g1;  qH[np] += g1 * g1;
            }
        }
    }
    __syncthreads();
    #pragma unroll
    for (int np = 0; np < 4; ++np) {
        int c = (np << 4) + (lane & 15);
        atomicAdd(&red[c], sL[np]);
        atomicAdd(&red[64 + c], sH[np]);
        atomicAdd(&red[128 + c], qL[np]);
        atomicAdd(&red[192 + c], qH[np]);
    }
    __syncthreads();
    atomicAdd(&statsOut[threadIdx.x], red[threadIdx.x]);
}

// ---- g-tier stats pass (fallback, R5): compute+store g, bn1 stats ----
template<int GF>   // 1 = fp32 g, 0 = fp16 g
__global__ __launch_bounds__(256) void k_gstat(const void* __restrict__ nbr_fea,
                       const int* __restrict__ nbr_idx,
                       const u16* __restrict__ An,
                       const float* __restrict__ Wst,
                       const float* __restrict__ Rf,
                       void* __restrict__ G,
                       float* __restrict__ statsOut,
                       const int* __restrict__ flag) {
    int f = flag[0];
    int lane = threadIdx.x & 63;
    int wv = threadIdx.x >> 6;
    int gwave = blockIdx.x * 4 + wv;
    int NW = gridDim.x * 4;
    __shared__ float2 wlds[NF][64];
    __shared__ float red[256];
    for (int i = threadIdx.x; i < NF * 64; i += 256) {
        int k = i >> 6, c = i & 63;
        wlds[k][c] = make_float2(Wst[(128 + k) * 128 + c],
                                 Wst[(128 + k) * 128 + 64 + c]);
    }
    __syncthreads();

    const u32* An32 = (const u32*)An;
    float sum0 = 0.f, ssq0 = 0.f, sum1 = 0.f, ssq1 = 0.f;

    for (int n = gwave; n < N_ATOM; n += NW) {
        float2 rr = *(const float2*)(Rf + ((long)n * 64 + lane) * 2);
        for (int mb = 0; mb < M_NBR; mb += 2) {
            long ra = (long)n * M_NBR + mb;
            int2 jj = *(const int2*)(nbr_idx + ra);
            float nv0, nv1;
            if (f) {
                const float* np = (const float*)nbr_fea + ra * NF;
                nv0 = (lane < NF) ? np[lane] : 0.f;
                nv1 = (lane < NF) ? np[NF + lane] : 0.f;
            } else {
                const u16* np = (const u16*)nbr_fea + ra * NF;
                nv0 = (lane < NF) ? b2f(np[lane]) : 0.f;
                nv1 = (lane < NF) ? b2f(np[NF + lane]) : 0.f;
            }
            u32 qa = An32[(long)jj.x * 64 + lane];
            u32 qb = An32[(long)jj.y * 64 + lane];
            float e00 = rr.x, e01 = rr.y, e10 = rr.x, e11 = rr.y;
            #pragma unroll
            for (int k = 0; k < NF; ++k) {
                float2 w = wlds[k][lane];
                float va = rdl(nv0, k);
                float vb = rdl(nv1, k);
                e00 = fmaf(va, w.x, e00);  e01 = fmaf(va, w.y, e01);
                e10 = fmaf(vb, w.x, e10);  e11 = fmaf(vb, w.y, e11);
            }
            float g00 = e00 + b2f((u16)(qa & 0xffffu));
            float g01 = e01 + b2f((u16)(qa >> 16));
            float g10 = e10 + b2f((u16)(qb & 0xffffu));
            float g11 = e11 + b2f((u16)(qb >> 16));
            if (GF) {
                float2* Gf = (float2*)G;
                Gf[(ra + 0) * 64 + lane] = make_float2(g00, g01);
                Gf[(ra + 1) * 64 + lane] = make_float2(g10, g11);
            } else {
                u32* Gh = (u32*)G;
                Gh[(ra + 0) * 64 + lane] = packh2(g00, g01);
                Gh[(ra + 1) * 64 + lane] = packh2(g10, g11);
            }
            sum0 += g00 + g10; ssq0 += g00 * g00 + g10 * g10;
            sum1 += g01 + g11; ssq1 += g01 * g01 + g11 * g11;
        }
    }

    red[threadIdx.x] = 0.f;
    __syncthreads();
    atomicAdd(&red[lane], sum0);
    atomicAdd(&red[64 + lane], sum1);
    atomicAdd(&red[128 + lane], ssq0);
    atomicAdd(&red[192 + lane], ssq1);
    __syncthreads();
    atomicAdd(&statsOut[threadIdx.x], red[threadIdx.x]);
}

// ---- g-tier apply pass: stream g, bn1 affine + sigmoid*softplus, atom sum ----
template<int GF>
__global__ __launch_bounds__(256) void k_gapply(const void* __restrict__ G,
                       const float* __restrict__ st1,
                       u16* __restrict__ summed,
                       float* __restrict__ statsOut) {
    int lane = threadIdx.x & 63;
    int wv = threadIdx.x >> 6;
    int gwave = blockIdx.x * 4 + wv;
    int NW = gridDim.x * 4;
    float s0 = st1[lane],        s1 = st1[lane + 64];
    float t0 = st1[128 + lane],  t1 = st1[192 + lane];
    float sum0 = 0.f, ssq0 = 0.f;
    for (int n = gwave; n < N_ATOM; n += NW) {
        float asum = 0.f;
        long base = (long)n * M_NBR * 64 + lane;
        #pragma unroll
        for (int m = 0; m < M_NBR; ++m) {
            float g0, g1;
            if (GF) {
                float2 g = ((const float2*)G)[base + (long)m * 64];
                g0 = g.x; g1 = g.y;
            } else {
                u32 gp = ((const u32*)G)[base + (long)m * 64];
                g0 = __half2float(__ushort_as_half((u16)(gp & 0xffffu)));
                g1 = __half2float(__ushort_as_half((u16)(gp >> 16)));
            }
            asum += sigf(fmaf(g0, s0, t0)) * spf(fmaf(g1, s1, t1));
        }
        summed[(long)n * 64 + lane] = f2b(asum);
        sum0 += asum; ssq0 += asum * asum;
    }
    __shared__ float red[256];
    if (threadIdx.x < 128) red[threadIdx.x] = 0.f;
    __syncthreads();
    atomicAdd(&red[lane], sum0);
    atomicAdd(&red[64 + lane], ssq0);
    __syncthreads();
    if (threadIdx.x < 128) atomicAdd(&statsOut[threadIdx.x], red[threadIdx.x]);
}

// ---- legacy conv sweep (small-ws fallback tiers; unchanged) ----
template<bool APPLY, int MODE>
__global__ __launch_bounds__(256) void k_conv(const void* __restrict__ nbr_fea,
                       const int* __restrict__ nbr_idx,
                       const u16* __restrict__ af, const u16* __restrict__ An,
                       const float* __restrict__ Wst, const float* __restrict__ bst,
                       const float* __restrict__ st1,
                       u16* __restrict__ summed,
                       float* __restrict__ statsOut,
                       const int* __restrict__ flag,
                       const float* __restrict__ Rf, const u16* __restrict__ Rh, int rf) {
    int f = flag[0];
    int lane = threadIdx.x & 63;
    int wv = threadIdx.x >> 6;
    int gwave = blockIdx.x * 4 + wv;
    int NW = gridDim.x * 4;
    __shared__ float2 wlds[NF][64];
    __shared__ float red[256];

    float s0 = 0.f, t0 = 0.f, s1 = 0.f, t1 = 0.f;
    if (APPLY) {
        s0 = st1[lane];        s1 = st1[lane + 64];
        t0 = st1[128 + lane];  t1 = st1[192 + lane];
    }
    float sum0 = 0.f, ssq0 = 0.f, sum1 = 0.f, ssq1 = 0.f;

    if (MODE == 0) {
        for (int i = threadIdx.x; i < NF * 64; i += 256) {
            int k = i >> 6, c = i & 63;
            wlds[k][c] = make_float2(Wst[(128 + k) * 128 + c],
                                     Wst[(128 + k) * 128 + 64 + c]);
        }
        __syncthreads();

        for (int n = gwave; n < N_ATOM; n += NW) {
            long p = (long)n * 64 + lane;
            float r0, r1;
            if (rf) {
                float2 rr = *(const float2*)(Rf + p * 2);
                r0 = rr.x; r1 = rr.y;
            } else {
                u32 rr = ((const u32*)Rh)[p];
                r0 = b2f((u16)(rr & 0xffffu)); r1 = b2f((u16)(rr >> 16));
            }
            float asum = 0.f;
            for (int m = 0; m < M_NBR; m += 2) {
                long ra = (long)n * M_NBR + m;
                int2 jj = *(const int2*)(nbr_idx + ra);
                float nv0, nv1;
                if (f) {
                    const float* np = (const float*)nbr_fea + ra * NF;
                    nv0 = (lane < NF) ? np[lane] : 0.f;
                    nv1 = (lane < NF) ? np[NF + lane] : 0.f;
                } else {
                    const u16* np = (const u16*)nbr_fea + ra * NF;
                    nv0 = (lane < NF) ? b2f(np[lane]) : 0.f;
                    nv1 = (lane < NF) ? b2f(np[NF + lane]) : 0.f;
                }
                u32 qa = ((const u32*)An)[(long)jj.x * 64 + lane];
                u32 qb = ((const u32*)An)[(long)jj.y * 64 + lane];
                float ea0 = r0, ea1 = r1, eb0 = r0, eb1 = r1;
                #pragma unroll
                for (int k = 0; k < NF; ++k) {
                    float2 w = wlds[k][lane];
                    float va = rdl(nv0, k);
                    float vb = rdl(nv1, k);
                    ea0 = fmaf(va, w.x, ea0);
                    ea1 = fmaf(va, w.y, ea1);
                    eb0 = fmaf(vb, w.x, eb0);
                    eb1 = fmaf(vb, w.y, eb1);
                }
                float ga0 = ea0 + b2f((u16)(qa & 0xffffu));
                float ga1 = ea1 + b2f((u16)(qa >> 16));
                float gb0 = eb0 + b2f((u16)(qb & 0xffffu));
                float gb1 = eb1 + b2f((u16)(qb >> 16));
                if (APPLY) {
                    asum += sigf(fmaf(ga0, s0, t0)) * spf(fmaf(ga1, s1, t1));
                    asum += sigf(fmaf(gb0, s0, t0)) * spf(fmaf(gb1, s1, t1));
                } else {
                    sum0 += ga0 + gb0; ssq0 += ga0 * ga0 + gb0 * gb0;
                    sum1 += ga1 + gb1; ssq1 += ga1 * ga1 + gb1 * gb1;
                }
            }
            if (APPLY) {
                summed[p] = f2b(asum);
                sum0 += asum; ssq0 += asum * asum;
            }
        }
    } else {
        float w0[NF], w1[NF];
        #pragma unroll
        for (int k = 0; k < NF; ++k) {
            w0[k] = Wst[(128 + k) * 128 + lane];
            w1[k] = Wst[(128 + k) * 128 + 64 + lane];
        }
        float b0 = bst[lane];
        float b1 = bst[64 + lane];
        for (int n = gwave; n < N_ATOM; n += NW) {
            float afv = b2f(af[n * AF + lane]);
            float as0 = b0, as1 = b1;
            for (int k = 0; k < AF; ++k) {
                float a = __shfl(afv, k, 64);
                as0 = fmaf(a, Wst[k * 128 + lane], as0);
                as1 = fmaf(a, Wst[k * 128 + 64 + lane], as1);
            }
            float asum = 0.f;
            for (int m = 0; m < M_NBR; ++m) {
                long r = (long)n * M_NBR + m;
                int j = nbr_idx[r];
                float nv = (lane < NF) ? ldf(nbr_fea, r * NF + lane, f) : 0.f;
                float e0 = as0, e1 = as1;
                #pragma unroll
                for (int k = 0; k < NF; ++k) {
                    float v = __shfl(nv, k, 64);
                    e0 = fmaf(v, w0[k], e0);
                    e1 = fmaf(v, w1[k], e1);
                }
                float g0, g1;
                if (MODE == 2) {
                    float aj = b2f(af[(long)j * AF + lane]);
                    float an0 = 0.f, an1 = 0.f;
                    for (int k = 0; k < AF; ++k) {
                        float a = __shfl(aj, k, 64);
                        an0 = fmaf(a, Wst[(AF + k) * 128 + lane], an0);
                        an1 = fmaf(a, Wst[(AF + k) * 128 + 64 + lane], an1);
                    }
                    g0 = e0 + an0; g1 = e1 + an1;
                } else {
                    g0 = e0 + b2f(An[(long)j * 128 + lane]);
                    g1 = e1 + b2f(An[(long)j * 128 + 64 + lane]);
                }
                if (APPLY) {
                    float ft = sigf(fmaf(g0, s0, t0));
                    float cc = spf(fmaf(g1, s1, t1));
                    asum += ft * cc;
                } else {
                    sum0 += g0; ssq0 += g0 * g0;
                    sum1 += g1; ssq1 += g1 * g1;
                }
            }
            if (APPLY) {
                summed[(long)n * 64 + lane] = f2b(asum);
                sum0 += asum; ssq0 += asum * asum;
            }
        }
    }

    if (APPLY) {
        if (threadIdx.x < 128) red[threadIdx.x] = 0.f;
        __syncthreads();
        atomicAdd(&red[lane], sum0);
        atomicAdd(&red[64 + lane], ssq0);
        __syncthreads();
        if (threadIdx.x < 128) atomicAdd(&statsOut[threadIdx.x], red[threadIdx.x]);
    } else {
        red[threadIdx.x] = 0.f;
        __syncthreads();
        atomicAdd(&red[lane], sum0);
        atomicAdd(&red[64 + lane], sum1);
        atomicAdd(&red[128 + lane], ssq0);
        atomicAdd(&red[192 + lane], ssq1);
        __syncthreads();
        atomicAdd(&statsOut[threadIdx.x], red[threadIdx.x]);
    }
}

__global__ void k_bn1(const float* __restrict__ stats, const float* __restrict__ bn1s,
                      float* __restrict__ st) {
    int c = threadIdx.x;  // 128
    float cnt = (float)N_ATOM * (float)M_NBR;
    float mu = stats[c] / cnt;
    float var = fmaxf(stats[128 + c] / cnt - mu * mu, 0.0f);
    float s = bn1s[c] * rsqrtf(var + EPS);
    st[c] = s;
    st[128 + c] = bn1s[128 + c] - mu * s;
}

__global__ void k_bn2(const float* __restrict__ stats, const float* __restrict__ bn2s,
                      float* __restrict__ st) {
    int c = threadIdx.x;  // 64
    float cnt = (float)N_ATOM;
    float mu = stats[c] / cnt;
    float var = fmaxf(stats[64 + c] / cnt - mu * mu, 0.0f);
    float s = bn2s[c] * rsqrtf(var + EPS);
    st[c] = s;
    st[64 + c] = bn2s[64 + c] - mu * s;
}

__global__ void k_update(u16* __restrict__ af, const u16* __restrict__ summed,
                         const float* __restrict__ st2) {
    int i = blockIdx.x * 256 + threadIdx.x;
    if (i < N_ATOM * 64) {
        int c = i & 63;
        float v = fmaf(b2f(summed[i]), st2[c], st2[64 + c]);
        af[i] = f2b(spf(b2f(af[i]) + v));
    }
}

__global__ void k_pool(const u16* __restrict__ af, const int* __restrict__ cidx,
                       float* __restrict__ crysp) {
    int b = blockIdx.x;
    int ch = threadIdx.x & 63;
    int part = threadIdx.x >> 6;
    float acc = 0.f;
    for (int k = part; k < APC; k += 4) {
        int a = cidx[b * APC + k];
        acc += b2f(af[(long)a * 64 + ch]);
    }
    __shared__ float red[256];
    red[threadIdx.x] = acc;
    __syncthreads();
    if (part == 0) {
        float s = red[ch] + red[64 + ch] + red[128 + ch] + red[192 + ch];
        crysp[b * 64 + ch] = spf(s * (1.0f / APC));
    }
}

__global__ void k_head(const float* __restrict__ crysp, const void* __restrict__ Wfc,
                       const void* __restrict__ bfc, const void* __restrict__ Wout,
                       const void* __restrict__ bout, void* __restrict__ outv,
                       const int* __restrict__ flag) {
    int f = flag[0];
    int b = blockIdx.x;
    int t = threadIdx.x;  // 128
    __shared__ float cr[64];
    __shared__ float h[HF];
    if (t < 64) cr[t] = crysp[b * 64 + t];
    __syncthreads();
    float acc = ldf(bfc, t, f);
    for (int k = 0; k < 64; ++k) acc = fmaf(cr[k], ldf(Wfc, (long)k * HF + t, f), acc);
    h[t] = spf(acc);
    __syncthreads();
    if (t < HID) {
        float o = ldf(bout, t, f);
        for (int k = 0; k < HF; ++k) o = fmaf(h[k], ldf(Wout, (long)k * HID + t, f), o);
        if (f) ((float*)outv)[b * HID + t] = o;
        else   ((u16*)outv)[b * HID + t] = f2b(o);
    }
}

extern "C" void kernel_launch(void* const* d_in, const int* in_sizes, int n_in,
                              void* d_out, int out_size, void* d_ws, size_t ws_size,
                              hipStream_t stream) {
    const int* atom_num = (const int*)d_in[0];
    const void* nbr_fea = d_in[1];
    const int* nbr_idx  = (const int*)d_in[2];
    const int* cidx     = (const int*)d_in[3];
    const void* emb     = d_in[4];
    const void* W_full  = d_in[5];
    const void* b_full  = d_in[6];
    const void* bn1_g   = d_in[7];
    const void* bn1_b   = d_in[8];
    const void* bn2_g   = d_in[9];
    const void* bn2_b   = d_in[10];
    const void* W_fc    = d_in[11];
    const void* b_fc    = d_in[12];
    const void* W_out   = d_in[13];
    const void* b_out   = d_in[14];

    // ---- ws layout: control + staging first, big arrays after ----
    char* wsb = (char*)d_ws;
    int*   flag   = (int*)wsb;                          // 16 B
    float* stats1 = (float*)(wsb + 16);                 // 256
    float* st1    = stats1 + 256;                       // 256
    float* stats2 = st1 + 256;                          // 128
    float* st2    = stats2 + 128;                       // 128
    float* crysp  = st2 + 128;                          // 6400
    float* Wst    = crysp + 6400;                       // 21632
    float* bst    = Wst + 21632;                        // 128
    float* bn1s   = bst + 128;                          // 256
    float* bn2s   = bn1s + 256;                         // 128
    u16*   af     = (u16*)(bn2s + 128);                 // N*64 bf16 = 12.8 MB
    u16*   summed = af + (long)N_ATOM * 64;             // N*64 bf16 = 12.8 MB
    u16*   An     = summed + (long)N_ATOM * 64;         // N*128 bf16 = 25.6 MB
    char*  afterAn = (char*)(An + (long)N_ATOM * 128);
    float* Rf = (float*)afterAn;                        // N*128 fp32 = 51.2 MB
    u16*   Rh = (u16*)afterAn;
    char*  afterRf = afterAn + (size_t)N_ATOM * 128 * 4;
    void*  G = (void*)afterRf;                          // g buffer

    size_t off_afterAn = (size_t)(afterAn - wsb);
    size_t need_f2  = off_afterAn + (size_t)N_ATOM * 128 * 4;
    size_t need_f2h = off_afterAn + (size_t)N_ATOM * 128 * 2;
    size_t need_f1  = off_afterAn;
    const size_t GBYTES32 = (size_t)N_ATOM * M_NBR * 128 * 4;  // 614.4 MB
    const size_t GBYTES16 = (size_t)N_ATOM * M_NBR * 128 * 2;  // 307.2 MB
    const size_t ABYTES   = (size_t)NTILE * 2048;              // 153.6 MB
    u32* Abuf = (u32*)(afterRf + GBYTES16);             // MFMA tier only
    size_t need_M  = need_f2 + GBYTES16 + ABYTES;       // ~589 MB
    size_t need_TA = need_f2 + GBYTES32;
    size_t need_TB = need_f2 + GBYTES16;
    int mf = (ws_size >= need_M) ? 1 : 0;
    int gf = (ws_size >= need_TA) ? 1 : ((ws_size >= need_TB) ? 0 : -1);
    int rf = (ws_size >= need_f2) ? 1 : ((ws_size >= need_f2h) ? 0 : -1);
    bool f1 = ws_size >= need_f1;

    k_probe<<<1, 256, 0, stream>>>((const u16*)nbr_fea, flag);
    if (mf) {
        k_nbrcvt<<<(int)(((long)NTILE * 512 + 255) / 256), 256, 0, stream>>>(
            nbr_fea, Abuf, flag);
    }
    k_embed<<<(N_ATOM * 64 + 255) / 256, 256, 0, stream>>>(atom_num, emb, af, flag);

    const long WROWS = (long)(2 * AF + NF) * 128;  // 21632
    for (int L = 0; L < NC; ++L) {
        (void)hipMemsetAsync(stats1, 0, 768 * sizeof(float), stream);
        k_stage<<<(int)((WROWS + 128 + 255) / 256), 256, 0, stream>>>(
            W_full, (long)L * WROWS, b_full, (long)L * 128,
            bn1_g, bn1_b, bn2_g, bn2_b, (long)L,
            Wst, bst, bn1s, bn2s, flag);
        if (mf) {
            // MFMA tier: edge GEMM on matrix cores, g stored fp16
            k_asn<<<N_ATOM / 4, 256, 0, stream>>>(af, Wst, bst, Rf, Rh, An, 1);
            k_gmfma<<<2500, 256, 0, stream>>>((const u16*)Abuf, nbr_idx, An, Wst,
                                              Rf, (u32*)G, stats1);
            k_bn1<<<1, 128, 0, stream>>>(stats1, bn1s, st1);
            k_gapply<0><<<2500, 256, 0, stream>>>(G, st1, summed, stats2);
        } else if (gf >= 0) {
            k_asn<<<N_ATOM / 4, 256, 0, stream>>>(af, Wst, bst, Rf, Rh, An, 1);
            if (gf == 1)
                k_gstat<1><<<2500, 256, 0, stream>>>(nbr_fea, nbr_idx, An, Wst, Rf,
                                                     G, stats1, flag);
            else
                k_gstat<0><<<2500, 256, 0, stream>>>(nbr_fea, nbr_idx, An, Wst, Rf,
                                                     G, stats1, flag);
            k_bn1<<<1, 128, 0, stream>>>(stats1, bn1s, st1);
            if (gf == 1)
                k_gapply<1><<<2500, 256, 0, stream>>>(G, st1, summed, stats2);
            else
                k_gapply<0><<<2500, 256, 0, stream>>>(G, st1, summed, stats2);
        } else if (rf >= 0) {
            k_asn<<<N_ATOM / 4, 256, 0, stream>>>(af, Wst, bst, Rf, Rh, An, rf);
            k_conv<false, 0><<<2500, 256, 0, stream>>>(nbr_fea, nbr_idx, af, An,
                Wst, bst, nullptr, nullptr, stats1, flag, Rf, Rh, rf);
            k_bn1<<<1, 128, 0, stream>>>(stats1, bn1s, st1);
            k_conv<true, 0><<<2500, 256, 0, stream>>>(nbr_fea, nbr_idx, af, An,
                Wst, bst, st1, summed, stats2, flag, Rf, Rh, rf);
        } else if (f1) {
            k_an<<<N_ATOM / 4, 256, 0, stream>>>(af, Wst, An);
            k_conv<false, 1><<<2500, 256, 0, stream>>>(nbr_fea, nbr_idx, af, An,
                Wst, bst, nullptr, nullptr, stats1, flag, nullptr, nullptr, 0);
            k_bn1<<<1, 128, 0, stream>>>(stats1, bn1s, st1);
            k_conv<true, 1><<<2500, 256, 0, stream>>>(nbr_fea, nbr_idx, af, An,
                Wst, bst, st1, summed, stats2, flag, nullptr, nullptr, 0);
        } else {
            k_conv<false, 2><<<2500, 256, 0, stream>>>(nbr_fea, nbr_idx, af, nullptr,
                Wst, bst, nullptr, nullptr, stats1, flag, nullptr, nullptr, 0);
            k_bn1<<<1, 128, 0, stream>>>(stats1, bn1s, st1);
            k_conv<true, 2><<<2500, 256, 0, stream>>>(nbr_fea, nbr_idx, af, nullptr,
                Wst, bst, st1, summed, stats2, flag, nullptr, nullptr, 0);
        }
        k_bn2<<<1, 64, 0, stream>>>(stats2, bn2s, st2);
        k_update<<<(N_ATOM * 64 + 255) / 256, 256, 0, stream>>>(af, summed, st2);
    }
    k_pool<<<N0C, 256, 0, stream>>>(af, cidx, crysp);
    k_head<<<N0C, HF, 0, stream>>>(crysp, W_fc, b_fc, W_out, b_out, d_out, flag);
}